// Round 6
// baseline (372.911 us; speedup 1.0000x reference)
//
#include <hip/hip_runtime.h>
#include <hip/hip_bf16.h>

#define B_   2
#define S_   2048
#define E_   2048
#define QKV_ 3072
#define NH   16
#define NKV  4
#define HD   128
#define SL   16   // conv_rope strip length

typedef __attribute__((ext_vector_type(8))) short bf16x8;
typedef __attribute__((ext_vector_type(4))) float f32x4;
typedef unsigned short u16;
typedef unsigned int   u32;

__device__ __forceinline__ float bf2f(u16 u) {
  union { u32 i; float f; } v; v.i = ((u32)u) << 16; return v.f;
}
__device__ __forceinline__ u16 f2bf(float f) {
  union { float f; u32 u; } v; v.f = f;
  return (u16)((v.u + 0x7FFFu + ((v.u >> 16) & 1u)) >> 16);
}
__device__ __forceinline__ u32 pkbf(float a, float b) {
  __hip_bfloat162 h = __float22bfloat162_rn(float2{a, b});
  u32 r; __builtin_memcpy(&r, &h, 4); return r;
}
__device__ __forceinline__ float ex2(float x) { return __builtin_amdgcn_exp2f(x); }
__device__ __forceinline__ u32 shf(u32 v, int l) { return (u32)__shfl((int)v, l); }
__device__ __forceinline__ void load_lds16(const u16* g, u16* l) {
  __builtin_amdgcn_global_load_lds((const __attribute__((address_space(1))) void*)g,
                                   (__attribute__((address_space(3))) void*)l, 16, 0, 0);
}

// ---------------- fp32 -> bf16 bulk convert (n multiple of 4) ----------------
__global__ __launch_bounds__(256) void f2b_conv(const float* __restrict__ in,
                                                u16* __restrict__ out, int n4) {
  const int i = blockIdx.x * 256 + threadIdx.x;
  if (i >= n4) return;
  const float4 v = ((const float4*)in)[i];
  ushort4 o;
  o.x = f2bf(v.x); o.y = f2bf(v.y); o.z = f2bf(v.z); o.w = f2bf(v.w);
  ((ushort4*)out)[i] = o;
}

// ---------------- rope table: cos/sin[s*64+i] ----------------
__global__ __launch_bounds__(256) void rope_tab(float* __restrict__ c,
                                                float* __restrict__ s) {
  const int idx = blockIdx.x * 256 + threadIdx.x;  // 2048*64
  const int t = idx >> 6, i = idx & 63;
  const float invf = powf(10000.0f, -(float)i * (1.0f / 64.0f));
  float sn, cs;
  sincosf((float)t * invf, &sn, &cs);
  c[idx] = cs; s[idx] = sn;
}

// ------------- 256x256 8-phase GEMM: C[M,N] = A[M,K]*B[N,K]^T + bias[N] -------------
// (unchanged — see round-3 comments for the schedule proof)
template <int OUT_BF16>
__global__ __launch_bounds__(512, 2) void gemm256(const u16* __restrict__ A,
                                                  const u16* __restrict__ Bm,
                                                  const float* __restrict__ bias,
                                                  void* __restrict__ C,
                                                  int M, int N, int K) {
  __shared__ u16 sm[2][2][256 * 64];   // [buf][0=A,1=B][row*64 + unit*8 + e]
  const int tid = threadIdx.x;
  const int lane = tid & 63;
  const int wave = tid >> 6;
  const int wm = wave >> 2, wn = wave & 3;
  const int L15 = lane & 15, Lq = lane >> 4;
  const int m0 = blockIdx.y * 256, n0 = blockIdx.x * 256;
  const int NT = K >> 6;

  const int srow = tid >> 3;
  const int sdst = (tid & 7) * 8;
  const int ssrc = ((tid & 7) ^ (srow & 7)) * 8;

  auto stageA = [&](int T, int h, int j) {
    const int row = h * 128 + j * 64 + srow;
    load_lds16(A + (size_t)(m0 + row) * K + T * 64 + ssrc,
               &sm[T & 1][0][row * 64 + sdst]);
  };
  auto stageB = [&](int T, int h, int j) {
    const int row = h * 128 + j * 64 + srow;
    load_lds16(Bm + (size_t)(n0 + row) * K + T * 64 + ssrc,
               &sm[T & 1][1][row * 64 + sdst]);
  };
  auto rdA = [&](int p, int ms, int mf, int kk) -> bf16x8 {
    const int row = wm * 128 + ms * 64 + mf * 16 + L15;
    const int u = (kk * 4 + Lq) ^ (row & 7);
    return *(const bf16x8*)&sm[p][0][row * 64 + u * 8];
  };
  auto rdB = [&](int p, int ns, int nf, int kk) -> bf16x8 {
    const int row = wn * 64 + ns * 32 + nf * 16 + L15;
    const int u = (kk * 4 + Lq) ^ (row & 7);
    return *(const bf16x8*)&sm[p][1][row * 64 + u * 8];
  };

  f32x4 acc[8][4] = {};

  stageA(0, 0, 0); stageA(0, 0, 1);
  stageB(0, 0, 0); stageB(0, 0, 1);
  stageA(0, 1, 0); stageA(0, 1, 1);
  stageB(0, 1, 0); stageB(0, 1, 1);
  stageB(1, 0, 0); stageB(1, 0, 1);
  stageA(1, 0, 0); stageA(1, 0, 1);
  asm volatile("s_waitcnt vmcnt(4)" ::: "memory");
  __builtin_amdgcn_s_barrier();

  bf16x8 af[4][2], bf0[2][2], bf1[2][2];

#define MFMA_QUAD(MS, NS, BF)                                                     \
  __builtin_amdgcn_s_setprio(1);                                                  \
  _Pragma("unroll")                                                               \
  for (int kk = 0; kk < 2; ++kk)                                                  \
    _Pragma("unroll")                                                             \
    for (int mf = 0; mf < 4; ++mf)                                                \
      _Pragma("unroll")                                                           \
      for (int nf = 0; nf < 2; ++nf)                                              \
        acc[MS * 4 + mf][NS * 2 + nf] = __builtin_amdgcn_mfma_f32_16x16x32_bf16(  \
            af[mf][kk], BF[nf][kk], acc[MS * 4 + mf][NS * 2 + nf], 0, 0, 0);      \
  __builtin_amdgcn_s_setprio(0);

  for (int T = 0; T < NT; ++T) {
    const int p = T & 1;
#pragma unroll
    for (int mf = 0; mf < 4; ++mf)
#pragma unroll
      for (int kk = 0; kk < 2; ++kk) af[mf][kk] = rdA(p, 0, mf, kk);
#pragma unroll
    for (int nf = 0; nf < 2; ++nf)
#pragma unroll
      for (int kk = 0; kk < 2; ++kk) bf0[nf][kk] = rdB(p, 0, nf, kk);
    if (T + 1 < NT) { stageA(T + 1, 1, 0); stageA(T + 1, 1, 1); }
    __builtin_amdgcn_s_barrier();
    MFMA_QUAD(0, 0, bf0)
    __builtin_amdgcn_s_barrier();
#pragma unroll
    for (int nf = 0; nf < 2; ++nf)
#pragma unroll
      for (int kk = 0; kk < 2; ++kk) bf1[nf][kk] = rdB(p, 1, nf, kk);
    if (T + 1 < NT) { stageB(T + 1, 1, 0); stageB(T + 1, 1, 1); }
    __builtin_amdgcn_s_barrier();
    MFMA_QUAD(0, 1, bf1)
    __builtin_amdgcn_s_barrier();
#pragma unroll
    for (int mf = 0; mf < 4; ++mf)
#pragma unroll
      for (int kk = 0; kk < 2; ++kk) af[mf][kk] = rdA(p, 1, mf, kk);
    if (T + 2 < NT) { stageB(T + 2, 0, 0); stageB(T + 2, 0, 1); }
    __builtin_amdgcn_s_barrier();
    MFMA_QUAD(1, 0, bf0)
    __builtin_amdgcn_s_barrier();
    if (T + 2 < NT) {
      stageA(T + 2, 0, 0); stageA(T + 2, 0, 1);
      asm volatile("s_waitcnt vmcnt(4)" ::: "memory");
    } else {
      asm volatile("s_waitcnt vmcnt(0)" ::: "memory");
    }
    __builtin_amdgcn_s_barrier();
    MFMA_QUAD(1, 1, bf1)
    __builtin_amdgcn_s_barrier();
  }
#undef MFMA_QUAD

#pragma unroll
  for (int ms = 0; ms < 2; ++ms)
#pragma unroll
    for (int mf = 0; mf < 4; ++mf) {
      const int grow0 = m0 + wm * 128 + ms * 64 + mf * 16 + Lq * 4;
#pragma unroll
      for (int ns = 0; ns < 2; ++ns)
#pragma unroll
        for (int nf = 0; nf < 2; ++nf) {
          const int gcol = n0 + wn * 64 + ns * 32 + nf * 16 + L15;
          const float bv = bias[gcol];
          const f32x4 v = acc[ms * 4 + mf][ns * 2 + nf];
#pragma unroll
          for (int r = 0; r < 4; ++r) {
            const float o = v[r] + bv;
            if (OUT_BF16) ((u16*)C)[(size_t)(grow0 + r) * N + gcol] = f2bf(o);
            else          ((float*)C)[(size_t)(grow0 + r) * N + gcol] = o;
          }
        }
    }
}

// ------------- 256x128 GEMM (grid-filling variant for N=2048): C = A*B^T + bias ----
// (unchanged)
__global__ __launch_bounds__(512, 2) void gemm_n128(const u16* __restrict__ A,
                                                    const u16* __restrict__ Bm,
                                                    const float* __restrict__ bias,
                                                    float* __restrict__ C,
                                                    int M, int N, int K) {
  __shared__ u16 sm[2][24576];  // [buf][ A 256*64 | B 128*64 ]
  const int tid = threadIdx.x, lane = tid & 63, wave = tid >> 6;
  const int wm = wave >> 1, wn = wave & 1;
  const int L15 = lane & 15, Lq = lane >> 4;
  const int m0 = blockIdx.y * 256, n0 = blockIdx.x * 128;
  const int NT = K >> 6;

  const int srow = tid >> 3;
  const int sdst = (tid & 7) * 8;
  const int ssrc = ((tid & 7) ^ (srow & 7)) * 8;

  auto stage6 = [&](int T) {
#pragma unroll
    for (int c = 0; c < 4; ++c) {
      const int row = c * 64 + srow;
      load_lds16(A + (size_t)(m0 + row) * K + T * 64 + ssrc,
                 &sm[T & 1][row * 64 + sdst]);
    }
#pragma unroll
    for (int c = 0; c < 2; ++c) {
      const int row = c * 64 + srow;
      load_lds16(Bm + (size_t)(n0 + row) * K + T * 64 + ssrc,
                 &sm[T & 1][16384 + row * 64 + sdst]);
    }
  };

  f32x4 acc[4][4] = {};
  stage6(0);

  for (int T = 0; T < NT; ++T) {
    const int p = T & 1;
    if (T + 1 < NT) {
      stage6(T + 1);
      asm volatile("s_waitcnt vmcnt(6)" ::: "memory");
    } else {
      asm volatile("s_waitcnt vmcnt(0)" ::: "memory");
    }
    __builtin_amdgcn_s_barrier();
    bf16x8 af[4][2], bfr[4][2];
#pragma unroll
    for (int mf = 0; mf < 4; ++mf)
#pragma unroll
      for (int kk = 0; kk < 2; ++kk) {
        const int row = wm * 64 + mf * 16 + L15;
        const int u = (kk * 4 + Lq) ^ (row & 7);
        af[mf][kk] = *(const bf16x8*)&sm[p][row * 64 + u * 8];
      }
#pragma unroll
    for (int nf = 0; nf < 4; ++nf)
#pragma unroll
      for (int kk = 0; kk < 2; ++kk) {
        const int row = wn * 64 + nf * 16 + L15;
        const int u = (kk * 4 + Lq) ^ (row & 7);
        bfr[nf][kk] = *(const bf16x8*)&sm[p][16384 + row * 64 + u * 8];
      }
    __builtin_amdgcn_s_setprio(1);
#pragma unroll
    for (int kk = 0; kk < 2; ++kk)
#pragma unroll
      for (int mf = 0; mf < 4; ++mf)
#pragma unroll
        for (int nf = 0; nf < 4; ++nf)
          acc[mf][nf] = __builtin_amdgcn_mfma_f32_16x16x32_bf16(
              af[mf][kk], bfr[nf][kk], acc[mf][nf], 0, 0, 0);
    __builtin_amdgcn_s_setprio(0);
    __builtin_amdgcn_s_barrier();
  }

#pragma unroll
  for (int mf = 0; mf < 4; ++mf) {
    const int grow0 = m0 + wm * 64 + mf * 16 + Lq * 4;
#pragma unroll
    for (int nf = 0; nf < 4; ++nf) {
      const int gcol = n0 + wn * 64 + nf * 16 + L15;
      const float bv = bias[gcol];
#pragma unroll
      for (int r = 0; r < 4; ++r)
        C[(size_t)(grow0 + r) * N + gcol] = acc[mf][nf][r] + bv;
    }
  }
}

// ------------- depthwise causal conv(4) + bias + RoPE, streaming over s -------------
__global__ __launch_bounds__(256) void conv_rope(const u16* __restrict__ qkv,
                                                 const float* __restrict__ cw,
                                                 const float* __restrict__ cb,
                                                 const float* __restrict__ ct,
                                                 const float* __restrict__ st,
                                                 u16* __restrict__ qo,
                                                 u16* __restrict__ ko,
                                                 u16* __restrict__ vtmp) {
  const int blk = blockIdx.x;                 // B * (S/SL)
  const int b = blk >> 7;                     // S/SL = 128
  const int s0 = (blk & 127) * SL;
  const u16* qb = qkv + (size_t)b * S_ * QKV_;

  for (int u = threadIdx.x; u < 896; u += 256) {
    if (u < 640) {
      // ---- rotary unit: features f1,f1+1 and f1+64,f1+65 ----
      const int hs = u >> 5, ip = u & 31, i = ip * 2;
      int f1; u16* outbase; float scale;
      if (hs < 16) {
        f1 = hs * HD + i;
        outbase = qo + (size_t)(b * NH + hs) * S_ * HD;
        scale = 0.08838834764831845f * 1.4426950408889634f;  // log2e/sqrt(128)
      } else {
        f1 = NH * HD + (hs - 16) * HD + i;
        outbase = ko + (size_t)(b * NKV + (hs - 16)) * S_ * HD;
        scale = 1.0f;
      }
      const int f2 = f1 + 64;
      const float4 wA0 = *(const float4*)&cw[f1 * 4];
      const float4 wA1 = *(const float4*)&cw[(f1 + 1) * 4];
      const float4 wB0 = *(const float4*)&cw[f2 * 4];
      const float4 wB1 = *(const float4*)&cw[(f2 + 1) * 4];
      const float cA0 = cb[f1], cA1 = cb[f1 + 1], cB0 = cb[f2], cB1 = cb[f2 + 1];
      float A0[3], A1[3], B0[3], B1[3];
#pragma unroll
      for (int j = 0; j < 3; ++j) {
        const int t = s0 - 3 + j;
        if (t >= 0) {
          const u32 pa = *(const u32*)&qb[(size_t)t * QKV_ + f1];
          const u32 pb = *(const u32*)&qb[(size_t)t * QKV_ + f2];
          A0[j] = bf2f((u16)pa); A1[j] = bf2f((u16)(pa >> 16));
          B0[j] = bf2f((u16)pb); B1[j] = bf2f((u16)(pb >> 16));
        } else { A0[j] = A1[j] = B0[j] = B1[j] = 0.f; }
      }
      for (int s = s0; s < s0 + SL; ++s) {
        const u32 pa = *(const u32*)&qb[(size_t)s * QKV_ + f1];
        const u32 pb = *(const u32*)&qb[(size_t)s * QKV_ + f2];
        const float nA0 = bf2f((u16)pa), nA1 = bf2f((u16)(pa >> 16));
        const float nB0 = bf2f((u16)pb), nB1 = bf2f((u16)(pb >> 16));
        const float x1a = cA0 + wA0.x * A0[0] + wA0.y * A0[1] + wA0.z * A0[2] + wA0.w * nA0;
        const float x1b = cA1 + wA1.x * A1[0] + wA1.y * A1[1] + wA1.z * A1[2] + wA1.w * nA1;
        const float x2a = cB0 + wB0.x * B0[0] + wB0.y * B0[1] + wB0.z * B0[2] + wB0.w * nB0;
        const float x2b = cB1 + wB1.x * B1[0] + wB1.y * B1[1] + wB1.z * B1[2] + wB1.w * nB1;
        const float2 cs = *(const float2*)&ct[s * 64 + i];
        const float2 sn = *(const float2*)&st[s * 64 + i];
        u16* outp = outbase + (size_t)s * HD;
        *(u32*)&outp[i]      = pkbf((x1a * cs.x - x2a * sn.x) * scale,
                                    (x1b * cs.y - x2b * sn.y) * scale);
        *(u32*)&outp[i + 64] = pkbf((x2a * cs.x + x1a * sn.x) * scale,
                                    (x2b * cs.y + x1b * sn.y) * scale);
        A0[0] = A0[1]; A0[1] = A0[2]; A0[2] = nA0;
        A1[0] = A1[1]; A1[1] = A1[2]; A1[2] = nA1;
        B0[0] = B0[1]; B0[1] = B0[2]; B0[2] = nB0;
        B1[0] = B1[1]; B1[1] = B1[2]; B1[2] = nB1;
      }
    } else {
      // ---- v unit: features f, f+1 ----
      const int vu = u - 640, h = vu >> 6, d = (vu & 63) * 2;
      const int f = (NH + NKV) * HD + h * HD + d;
      const float4 w0 = *(const float4*)&cw[f * 4];
      const float4 w1 = *(const float4*)&cw[(f + 1) * 4];
      const float c0 = cb[f], c1 = cb[f + 1];
      float V0[3], V1[3];
#pragma unroll
      for (int j = 0; j < 3; ++j) {
        const int t = s0 - 3 + j;
        if (t >= 0) {
          const u32 p = *(const u32*)&qb[(size_t)t * QKV_ + f];
          V0[j] = bf2f((u16)p); V1[j] = bf2f((u16)(p >> 16));
        } else { V0[j] = V1[j] = 0.f; }
      }
      u16* vrow = vtmp + (size_t)(b * NKV + h) * S_ * HD + d;
      for (int s = s0; s < s0 + SL; ++s) {
        const u32 p = *(const u32*)&qb[(size_t)s * QKV_ + f];
        const float n0 = bf2f((u16)p), n1 = bf2f((u16)(p >> 16));
        const float v0 = c0 + w0.x * V0[0] + w0.y * V0[1] + w0.z * V0[2] + w0.w * n0;
        const float v1 = c1 + w1.x * V1[0] + w1.y * V1[1] + w1.z * V1[2] + w1.w * n1;
        *(u32*)&vrow[(size_t)s * HD] = pkbf(v0, v1);
        V0[0] = V0[1]; V0[1] = V0[2]; V0[2] = n0;
        V1[0] = V1[1]; V1[1] = V1[2]; V1[2] = n1;
      }
    }
  }
}

// ---------------- v (B,NKV,S,HD) -> v^T (B,NKV,HD,S), 64x64 LDS tiles ----------------
__global__ __launch_bounds__(256) void vtrans(const u16* __restrict__ vin,
                                              u16* __restrict__ vout) {
  __shared__ u16 t[64][72];
  const int bh = blockIdx.z;
  const int d0 = blockIdx.y * 64;
  const int s0 = blockIdx.x * 64;
  const u16* ip = vin + ((size_t)bh * S_ + s0) * HD + d0;
  const int r = threadIdx.x >> 4, c4 = (threadIdx.x & 15) * 4;
#pragma unroll
  for (int j = 0; j < 4; ++j) {
    const ushort4 v = *(const ushort4*)&ip[(size_t)(r + j * 16) * HD + c4];
    t[c4 + 0][r + j * 16] = v.x;
    t[c4 + 1][r + j * 16] = v.y;
    t[c4 + 2][r + j * 16] = v.z;
    t[c4 + 3][r + j * 16] = v.w;
  }
  __syncthreads();
  const int dl = threadIdx.x >> 2, sc = (threadIdx.x & 3) * 16;
  u16* op = vout + (size_t)bh * HD * S_ + (size_t)(d0 + dl) * S_ + s0 + sc;
  *(bf16x8*)op       = *(const bf16x8*)&t[dl][sc];
  *(bf16x8*)(op + 8) = *(const bf16x8*)&t[dl][sc + 8];
}

// ------------------------- flash attention (causal, GQA) -------------------------
// Round-4 body (known-good 78 µs), UNPAIRED grid: each block owns one 64-row
// q-tile; grid (32, B*NH) = 1024 blocks, 4x oversubscribed -> triangular work
// load-balances dynamically. LDS 48 KB + launch_bounds(256,3) -> 3 blocks/CU
// resident (was 2), filling the ~50% no-issue gap. Swapped QK^T, in-register P,
// defer-max, counted vmcnt(4) mid-barrier (K(kt+1) stays in flight).
__global__ __launch_bounds__(256, 3) void attn(const u16* __restrict__ q,
                                               const u16* __restrict__ k,
                                               const u16* __restrict__ v,
                                               u16* __restrict__ ctx) {
  __shared__ u16 Ks[2][64 * 128];
  __shared__ u16 Vs[128 * 64];
  const int tid = threadIdx.x, wave = tid >> 6, lane = tid & 63;
  const int L15 = lane & 15, Lq = lane >> 4;
  const int bh = blockIdx.y;
  const int b = bh >> 4, h = bh & 15, hk = h >> 2;

  const u16* kb = k + (size_t)(b * NKV + hk) * S_ * HD;
  const u16* vb = v + (size_t)(b * NKV + hk) * HD * S_;

  const int rx = L15 & 7;
  int koff[4], voff[2];
#pragma unroll
  for (int c = 0; c < 4; ++c) koff[c] = ((c * 4 + Lq) ^ rx) * 8;
#pragma unroll
  for (int kc = 0; kc < 2; ++kc) voff[kc] = ((kc * 4 + Lq) ^ rx) * 8;

  const int ksl = tid >> 4, kcp = tid & 15;
  const int vsl = tid >> 3, vcp = tid & 7;

  // repack geometry: word W of pa[kc] comes from lane (2*(Lq&1)+(W>>1))*16+L15,
  // value w[2kc + (Lq>>1)][W&1]
  const int ls0 = ((Lq & 1) << 5) + L15;
  const int ls1 = ls0 + 16;
  const bool hi = (Lq & 2) != 0;

  const int qt = blockIdx.x;
  const int q0 = qt * 64;
  const int base = q0 + wave * 16;

  bf16x8 qf[4];
  {
    const u16* qp = q + ((size_t)bh * S_ + base + L15) * HD + Lq * 8;
#pragma unroll
    for (int c = 0; c < 4; ++c) qf[c] = *(const bf16x8*)(qp + c * 32);
  }

  f32x4 acc[8] = {};
  float m_i = -1e30f, l_i = 0.f;   // per-lane scalars for q = base + L15

  const int ktmax = qt + 1;

  // preamble: stage K(0) and V(0)
#pragma unroll
  for (int j = 0; j < 4; ++j) {
    const int krow = j * 16 + ksl;
    load_lds16(kb + (size_t)krow * HD + (kcp ^ (krow & 7)) * 8,
               &Ks[0][(krow * 16 + kcp) * 8]);
    const int vrow = j * 32 + vsl;
    load_lds16(vb + (size_t)vrow * S_ + (vcp ^ (vrow & 7)) * 8,
               &Vs[(vrow * 8 + vcp) * 8]);
  }
  __syncthreads();

  for (int kt = 0; kt < ktmax; ++kt) {
    const int k0 = kt * 64;
    const int cur = kt & 1;
    if (kt > 0) {  // V(kt): buffer free since end-barrier of kt-1
#pragma unroll
      for (int j = 0; j < 4; ++j) {
        const int vrow = j * 32 + vsl;
        load_lds16(vb + (size_t)vrow * S_ + k0 + (vcp ^ (vrow & 7)) * 8,
                   &Vs[(vrow * 8 + vcp) * 8]);
      }
    }
    if (kt + 1 < ktmax) {  // K(kt+1) into other K buffer
      const int kn = k0 + 64;
#pragma unroll
      for (int j = 0; j < 4; ++j) {
        const int krow = j * 16 + ksl;
        load_lds16(kb + (size_t)(kn + krow) * HD + (kcp ^ (krow & 7)) * 8,
                   &Ks[cur ^ 1][(krow * 16 + kcp) * 8]);
      }
    }
    // ---- swapped QK^T: sc[nt][r] = S[q=base+L15][k=k0+nt*16+Lq*4+r] ----
    f32x4 sc[4];
#pragma unroll
    for (int nt = 0; nt < 4; ++nt) sc[nt] = f32x4{0.f, 0.f, 0.f, 0.f};
#pragma unroll
    for (int nt = 0; nt < 4; ++nt) {
#pragma unroll
      for (int c = 0; c < 4; ++c) {
        const bf16x8 kf = *(const bf16x8*)&Ks[cur][(nt * 16 + L15) * 128 + koff[c]];
        sc[nt] = __builtin_amdgcn_mfma_f32_16x16x32_bf16(kf, qf[c], sc[nt], 0, 0, 0);
      }
    }
    if (k0 + 63 > base) {  // diagonal tile: causal mask
#pragma unroll
      for (int nt = 0; nt < 4; ++nt)
#pragma unroll
        for (int r = 0; r < 4; ++r) {
          const int kidx = k0 + nt * 16 + Lq * 4 + r;
          if (kidx > base + L15) sc[nt][r] = -1e30f;
        }
    }
    // ---- row max (in-lane tree + 2 shfl) ----
    float mloc = fmaxf(fmaxf(fmaxf(sc[0][0], sc[0][1]), fmaxf(sc[0][2], sc[0][3])),
                       fmaxf(fmaxf(sc[1][0], sc[1][1]), fmaxf(sc[1][2], sc[1][3])));
    mloc = fmaxf(mloc,
                 fmaxf(fmaxf(fmaxf(sc[2][0], sc[2][1]), fmaxf(sc[2][2], sc[2][3])),
                       fmaxf(fmaxf(sc[3][0], sc[3][1]), fmaxf(sc[3][2], sc[3][3]))));
    mloc = fmaxf(mloc, __shfl_xor(mloc, 16));
    mloc = fmaxf(mloc, __shfl_xor(mloc, 32));
    // ---- defer-max online update ----
    const bool defer = __all(mloc - m_i <= 8.f);
    if (!defer) {
      const float mnew = fmaxf(m_i, mloc);
      const float alpha = ex2(m_i - mnew);
      m_i = mnew;
      l_i *= alpha;
      float aacc[4];
#pragma unroll
      for (int r = 0; r < 4; ++r) aacc[r] = __shfl(alpha, Lq * 4 + r);
#pragma unroll
      for (int dt = 0; dt < 8; ++dt)
#pragma unroll
        for (int r = 0; r < 4; ++r) acc[dt][r] *= aacc[r];
    }
    // ---- P = exp2(S - m), row sum ----
    float lsum = 0.f;
#pragma unroll
    for (int nt = 0; nt < 4; ++nt)
#pragma unroll
      for (int r = 0; r < 4; ++r) {
        sc[nt][r] = ex2(sc[nt][r] - m_i);
        lsum += sc[nt][r];
      }
    lsum += __shfl_xor(lsum, 16);
    lsum += __shfl_xor(lsum, 32);
    l_i += lsum;
    // ---- pack P pairs: w[nt][j] = k = nt*16 + Lq*4 + 2j + {0,1} ----
    u32 wA[2], wB[2], wC[2], wD[2];
    wA[0] = pkbf(sc[0][0], sc[0][1]); wA[1] = pkbf(sc[0][2], sc[0][3]);
    wB[0] = pkbf(sc[1][0], sc[1][1]); wB[1] = pkbf(sc[1][2], sc[1][3]);
    wC[0] = pkbf(sc[2][0], sc[2][1]); wC[1] = pkbf(sc[2][2], sc[2][3]);
    wD[0] = pkbf(sc[3][0], sc[3][1]); wD[1] = pkbf(sc[3][2], sc[3][3]);
    // ---- cross-lane repack -> pa[kc] = P[q=L15][k=kc*32+Lq*8+e] ----
    bf16x8 pa[2];
    {
      union { u32 u[4]; bf16x8 v; } t0, t1;
      u32 x0, x1;
      x0 = shf(wA[0], ls0); x1 = shf(wB[0], ls0); t0.u[0] = hi ? x1 : x0;
      x0 = shf(wA[1], ls0); x1 = shf(wB[1], ls0); t0.u[1] = hi ? x1 : x0;
      x0 = shf(wA[0], ls1); x1 = shf(wB[0], ls1); t0.u[2] = hi ? x1 : x0;
      x0 = shf(wA[1], ls1); x1 = shf(wB[1], ls1); t0.u[3] = hi ? x1 : x0;
      x0 = shf(wC[0], ls0); x1 = shf(wD[0], ls0); t1.u[0] = hi ? x1 : x0;
      x0 = shf(wC[1], ls0); x1 = shf(wD[1], ls0); t1.u[1] = hi ? x1 : x0;
      x0 = shf(wC[0], ls1); x1 = shf(wD[0], ls1); t1.u[2] = hi ? x1 : x0;
      x0 = shf(wC[1], ls1); x1 = shf(wD[1], ls1); t1.u[3] = hi ? x1 : x0;
      pa[0] = t0.v; pa[1] = t1.v;
    }
    // ---- M barrier: retire V(kt) only; K(kt+1) stays in flight ----
    if (kt + 1 < ktmax) asm volatile("s_waitcnt vmcnt(4)" ::: "memory");
    else                asm volatile("s_waitcnt vmcnt(0)" ::: "memory");
    __builtin_amdgcn_s_barrier();
    asm volatile("" ::: "memory");
    // ---- PV from Vs ----
#pragma unroll
    for (int dt = 0; dt < 8; ++dt)
#pragma unroll
      for (int kc = 0; kc < 2; ++kc) {
        const bf16x8 vf = *(const bf16x8*)&Vs[(dt * 16 + L15) * 64 + voff[kc]];
        acc[dt] = __builtin_amdgcn_mfma_f32_16x16x32_bf16(pa[kc], vf, acc[dt], 0, 0, 0);
      }
    __syncthreads();  // E: V reads done + K(kt+1) drained before next iter
  }
  // ---- epilogue ----
  {
    float inv[4];
#pragma unroll
    for (int r = 0; r < 4; ++r) inv[r] = 1.f / __shfl(l_i, Lq * 4 + r);
    u16* cp = ctx + ((size_t)b * S_ + base) * (NH * HD) + h * HD;
#pragma unroll
    for (int dt = 0; dt < 8; ++dt)
#pragma unroll
      for (int rp = 0; rp < 2; ++rp) {
        const u32 pk = pkbf(acc[dt][rp * 2] * inv[rp * 2],
                            acc[dt][rp * 2 + 1] * inv[rp * 2 + 1]);
        cp[(size_t)(Lq * 4 + rp * 2) * (NH * HD) + dt * 16 + L15] = (u16)pk;
        cp[(size_t)(Lq * 4 + rp * 2 + 1) * (NH * HD) + dt * 16 + L15] = (u16)(pk >> 16);
      }
  }
}

extern "C" void kernel_launch(void* const* d_in, const int* in_sizes, int n_in,
                              void* d_out, int out_size, void* d_ws, size_t ws_size,
                              hipStream_t stream) {
  const float* x     = (const float*)d_in[0];
  const float* W_in  = (const float*)d_in[1];
  const float* b_in  = (const float*)d_in[2];
  const float* cw    = (const float*)d_in[3];
  const float* cb    = (const float*)d_in[4];
  const float* W_out = (const float*)d_in[5];
  const float* b_out = (const float*)d_in[6];

  char* ws = (char*)d_ws;
  u16* xb   = (u16*)(ws);                    // 16777216 B (dead after gemm1)
  u16* wib  = (u16*)(ws + 16777216);         // 12582912 B (dead after gemm1)
  u16* wob  = (u16*)(ws + 29360128);         //  8388608 B
  u16* qkv  = (u16*)(ws + 37748736);         // 25165824 B
  u16* q_ws = (u16*)(ws + 62914560);         // 16777216 B
  u16* k_ws = (u16*)(ws + 79691776);         //  4194304 B
  u16* vt_ws= (u16*)(ws + 83886080);         //  4194304 B
  float* ctab = (float*)ws;                  // rope tables in dead xb region
  float* stab = (float*)(ws + 524288);
  u16* vtmp = wib;                           // v row-major, in dead wib region
  u16* ctx  = xb;                            // alias: xb dead after gemm1

  const int nx = B_ * S_ * E_ / 4, nwi = QKV_ * E_ / 4, nwo = E_ * NH * HD / 4;
  f2b_conv<<<dim3((nx  + 255) / 256), 256, 0, stream>>>(x,     xb,  nx);
  f2b_conv<<<dim3((nwi + 255) / 256), 256, 0, stream>>>(W_in,  wib, nwi);
  f2b_conv<<<dim3((nwo + 255) / 256), 256, 0, stream>>>(W_out, wob, nwo);

  gemm256<1><<<dim3(QKV_ / 256, (B_ * S_) / 256), 512, 0, stream>>>(
      xb, wib, b_in, (void*)qkv, B_ * S_, QKV_, E_);
  rope_tab<<<dim3(S_ * 64 / 256), 256, 0, stream>>>(ctab, stab);
  conv_rope<<<dim3(B_ * (S_ / SL)), 256, 0, stream>>>(qkv, cw, cb, ctab, stab, q_ws, k_ws, vtmp);
  vtrans<<<dim3(S_ / 64, HD / 64, B_ * NKV), 256, 0, stream>>>(vtmp, vt_ws);
  attn<<<dim3(32, B_ * NH), 256, 0, stream>>>(q_ws, k_ws, vt_ws, ctx);
  gemm_n128<<<dim3(E_ / 128, (B_ * S_) / 256), 512, 0, stream>>>(
      ctx, wob, b_out, (float*)d_out, B_ * S_, E_, NH * HD);
}

// Round 7
// 332.182 us; speedup vs baseline: 1.1226x; 1.1226x over previous
//
#include <hip/hip_runtime.h>
#include <hip/hip_bf16.h>

#define B_   2
#define S_   2048
#define E_   2048
#define QKV_ 3072
#define NH   16
#define NKV  4
#define HD   128
#define SL   16   // conv_rope strip length

typedef __attribute__((ext_vector_type(8))) short bf16x8;
typedef __attribute__((ext_vector_type(4))) float f32x4;
typedef unsigned short u16;
typedef unsigned int   u32;

__device__ __forceinline__ float bf2f(u16 u) {
  union { u32 i; float f; } v; v.i = ((u32)u) << 16; return v.f;
}
__device__ __forceinline__ u16 f2bf(float f) {
  union { float f; u32 u; } v; v.f = f;
  return (u16)((v.u + 0x7FFFu + ((v.u >> 16) & 1u)) >> 16);
}
__device__ __forceinline__ u32 pkbf(float a, float b) {
  __hip_bfloat162 h = __float22bfloat162_rn(float2{a, b});
  u32 r; __builtin_memcpy(&r, &h, 4); return r;
}
__device__ __forceinline__ float ex2(float x) { return __builtin_amdgcn_exp2f(x); }
__device__ __forceinline__ u32 shf(u32 v, int l) { return (u32)__shfl((int)v, l); }
__device__ __forceinline__ void load_lds16(const u16* g, u16* l) {
  __builtin_amdgcn_global_load_lds((const __attribute__((address_space(1))) void*)g,
                                   (__attribute__((address_space(3))) void*)l, 16, 0, 0);
}

// ---------------- fp32 -> bf16 bulk convert (n multiple of 4) ----------------
__global__ __launch_bounds__(256) void f2b_conv(const float* __restrict__ in,
                                                u16* __restrict__ out, int n4) {
  const int i = blockIdx.x * 256 + threadIdx.x;
  if (i >= n4) return;
  const float4 v = ((const float4*)in)[i];
  ushort4 o;
  o.x = f2bf(v.x); o.y = f2bf(v.y); o.z = f2bf(v.z); o.w = f2bf(v.w);
  ((ushort4*)out)[i] = o;
}

// ---------------- rope table: cos/sin[s*64+i] ----------------
__global__ __launch_bounds__(256) void rope_tab(float* __restrict__ c,
                                                float* __restrict__ s) {
  const int idx = blockIdx.x * 256 + threadIdx.x;  // 2048*64
  const int t = idx >> 6, i = idx & 63;
  const float invf = powf(10000.0f, -(float)i * (1.0f / 64.0f));
  float sn, cs;
  sincosf((float)t * invf, &sn, &cs);
  c[idx] = cs; s[idx] = sn;
}

// ------------- 256x256 8-phase GEMM: C[M,N] = A[M,K]*B[N,K]^T + bias[N] -------------
// (unchanged — see round-3 comments for the schedule proof)
template <int OUT_BF16>
__global__ __launch_bounds__(512, 2) void gemm256(const u16* __restrict__ A,
                                                  const u16* __restrict__ Bm,
                                                  const float* __restrict__ bias,
                                                  void* __restrict__ C,
                                                  int M, int N, int K) {
  __shared__ u16 sm[2][2][256 * 64];   // [buf][0=A,1=B][row*64 + unit*8 + e]
  const int tid = threadIdx.x;
  const int lane = tid & 63;
  const int wave = tid >> 6;
  const int wm = wave >> 2, wn = wave & 3;
  const int L15 = lane & 15, Lq = lane >> 4;
  const int m0 = blockIdx.y * 256, n0 = blockIdx.x * 256;
  const int NT = K >> 6;

  const int srow = tid >> 3;
  const int sdst = (tid & 7) * 8;
  const int ssrc = ((tid & 7) ^ (srow & 7)) * 8;

  auto stageA = [&](int T, int h, int j) {
    const int row = h * 128 + j * 64 + srow;
    load_lds16(A + (size_t)(m0 + row) * K + T * 64 + ssrc,
               &sm[T & 1][0][row * 64 + sdst]);
  };
  auto stageB = [&](int T, int h, int j) {
    const int row = h * 128 + j * 64 + srow;
    load_lds16(Bm + (size_t)(n0 + row) * K + T * 64 + ssrc,
               &sm[T & 1][1][row * 64 + sdst]);
  };
  auto rdA = [&](int p, int ms, int mf, int kk) -> bf16x8 {
    const int row = wm * 128 + ms * 64 + mf * 16 + L15;
    const int u = (kk * 4 + Lq) ^ (row & 7);
    return *(const bf16x8*)&sm[p][0][row * 64 + u * 8];
  };
  auto rdB = [&](int p, int ns, int nf, int kk) -> bf16x8 {
    const int row = wn * 64 + ns * 32 + nf * 16 + L15;
    const int u = (kk * 4 + Lq) ^ (row & 7);
    return *(const bf16x8*)&sm[p][1][row * 64 + u * 8];
  };

  f32x4 acc[8][4] = {};

  stageA(0, 0, 0); stageA(0, 0, 1);
  stageB(0, 0, 0); stageB(0, 0, 1);
  stageA(0, 1, 0); stageA(0, 1, 1);
  stageB(0, 1, 0); stageB(0, 1, 1);
  stageB(1, 0, 0); stageB(1, 0, 1);
  stageA(1, 0, 0); stageA(1, 0, 1);
  asm volatile("s_waitcnt vmcnt(4)" ::: "memory");
  __builtin_amdgcn_s_barrier();

  bf16x8 af[4][2], bf0[2][2], bf1[2][2];

#define MFMA_QUAD(MS, NS, BF)                                                     \
  __builtin_amdgcn_s_setprio(1);                                                  \
  _Pragma("unroll")                                                               \
  for (int kk = 0; kk < 2; ++kk)                                                  \
    _Pragma("unroll")                                                             \
    for (int mf = 0; mf < 4; ++mf)                                                \
      _Pragma("unroll")                                                           \
      for (int nf = 0; nf < 2; ++nf)                                              \
        acc[MS * 4 + mf][NS * 2 + nf] = __builtin_amdgcn_mfma_f32_16x16x32_bf16(  \
            af[mf][kk], BF[nf][kk], acc[MS * 4 + mf][NS * 2 + nf], 0, 0, 0);      \
  __builtin_amdgcn_s_setprio(0);

  for (int T = 0; T < NT; ++T) {
    const int p = T & 1;
#pragma unroll
    for (int mf = 0; mf < 4; ++mf)
#pragma unroll
      for (int kk = 0; kk < 2; ++kk) af[mf][kk] = rdA(p, 0, mf, kk);
#pragma unroll
    for (int nf = 0; nf < 2; ++nf)
#pragma unroll
      for (int kk = 0; kk < 2; ++kk) bf0[nf][kk] = rdB(p, 0, nf, kk);
    if (T + 1 < NT) { stageA(T + 1, 1, 0); stageA(T + 1, 1, 1); }
    __builtin_amdgcn_s_barrier();
    MFMA_QUAD(0, 0, bf0)
    __builtin_amdgcn_s_barrier();
#pragma unroll
    for (int nf = 0; nf < 2; ++nf)
#pragma unroll
      for (int kk = 0; kk < 2; ++kk) bf1[nf][kk] = rdB(p, 1, nf, kk);
    if (T + 1 < NT) { stageB(T + 1, 1, 0); stageB(T + 1, 1, 1); }
    __builtin_amdgcn_s_barrier();
    MFMA_QUAD(0, 1, bf1)
    __builtin_amdgcn_s_barrier();
#pragma unroll
    for (int mf = 0; mf < 4; ++mf)
#pragma unroll
      for (int kk = 0; kk < 2; ++kk) af[mf][kk] = rdA(p, 1, mf, kk);
    if (T + 2 < NT) { stageB(T + 2, 0, 0); stageB(T + 2, 0, 1); }
    __builtin_amdgcn_s_barrier();
    MFMA_QUAD(1, 0, bf0)
    __builtin_amdgcn_s_barrier();
    if (T + 2 < NT) {
      stageA(T + 2, 0, 0); stageA(T + 2, 0, 1);
      asm volatile("s_waitcnt vmcnt(4)" ::: "memory");
    } else {
      asm volatile("s_waitcnt vmcnt(0)" ::: "memory");
    }
    __builtin_amdgcn_s_barrier();
    MFMA_QUAD(1, 1, bf1)
    __builtin_amdgcn_s_barrier();
  }
#undef MFMA_QUAD

#pragma unroll
  for (int ms = 0; ms < 2; ++ms)
#pragma unroll
    for (int mf = 0; mf < 4; ++mf) {
      const int grow0 = m0 + wm * 128 + ms * 64 + mf * 16 + Lq * 4;
#pragma unroll
      for (int ns = 0; ns < 2; ++ns)
#pragma unroll
        for (int nf = 0; nf < 2; ++nf) {
          const int gcol = n0 + wn * 64 + ns * 32 + nf * 16 + L15;
          const float bv = bias[gcol];
          const f32x4 v = acc[ms * 4 + mf][ns * 2 + nf];
#pragma unroll
          for (int r = 0; r < 4; ++r) {
            const float o = v[r] + bv;
            if (OUT_BF16) ((u16*)C)[(size_t)(grow0 + r) * N + gcol] = f2bf(o);
            else          ((float*)C)[(size_t)(grow0 + r) * N + gcol] = o;
          }
        }
    }
}

// ------------- 256x128 GEMM (grid-filling variant for N=2048): C = A*B^T + bias ----
// (unchanged)
__global__ __launch_bounds__(512, 2) void gemm_n128(const u16* __restrict__ A,
                                                    const u16* __restrict__ Bm,
                                                    const float* __restrict__ bias,
                                                    float* __restrict__ C,
                                                    int M, int N, int K) {
  __shared__ u16 sm[2][24576];  // [buf][ A 256*64 | B 128*64 ]
  const int tid = threadIdx.x, lane = tid & 63, wave = tid >> 6;
  const int wm = wave >> 1, wn = wave & 1;
  const int L15 = lane & 15, Lq = lane >> 4;
  const int m0 = blockIdx.y * 256, n0 = blockIdx.x * 128;
  const int NT = K >> 6;

  const int srow = tid >> 3;
  const int sdst = (tid & 7) * 8;
  const int ssrc = ((tid & 7) ^ (srow & 7)) * 8;

  auto stage6 = [&](int T) {
#pragma unroll
    for (int c = 0; c < 4; ++c) {
      const int row = c * 64 + srow;
      load_lds16(A + (size_t)(m0 + row) * K + T * 64 + ssrc,
                 &sm[T & 1][row * 64 + sdst]);
    }
#pragma unroll
    for (int c = 0; c < 2; ++c) {
      const int row = c * 64 + srow;
      load_lds16(Bm + (size_t)(n0 + row) * K + T * 64 + ssrc,
                 &sm[T & 1][16384 + row * 64 + sdst]);
    }
  };

  f32x4 acc[4][4] = {};
  stage6(0);

  for (int T = 0; T < NT; ++T) {
    const int p = T & 1;
    if (T + 1 < NT) {
      stage6(T + 1);
      asm volatile("s_waitcnt vmcnt(6)" ::: "memory");
    } else {
      asm volatile("s_waitcnt vmcnt(0)" ::: "memory");
    }
    __builtin_amdgcn_s_barrier();
    bf16x8 af[4][2], bfr[4][2];
#pragma unroll
    for (int mf = 0; mf < 4; ++mf)
#pragma unroll
      for (int kk = 0; kk < 2; ++kk) {
        const int row = wm * 64 + mf * 16 + L15;
        const int u = (kk * 4 + Lq) ^ (row & 7);
        af[mf][kk] = *(const bf16x8*)&sm[p][row * 64 + u * 8];
      }
#pragma unroll
    for (int nf = 0; nf < 4; ++nf)
#pragma unroll
      for (int kk = 0; kk < 2; ++kk) {
        const int row = wn * 64 + nf * 16 + L15;
        const int u = (kk * 4 + Lq) ^ (row & 7);
        bfr[nf][kk] = *(const bf16x8*)&sm[p][16384 + row * 64 + u * 8];
      }
    __builtin_amdgcn_s_setprio(1);
#pragma unroll
    for (int kk = 0; kk < 2; ++kk)
#pragma unroll
      for (int mf = 0; mf < 4; ++mf)
#pragma unroll
        for (int nf = 0; nf < 4; ++nf)
          acc[mf][nf] = __builtin_amdgcn_mfma_f32_16x16x32_bf16(
              af[mf][kk], bfr[nf][kk], acc[mf][nf], 0, 0, 0);
    __builtin_amdgcn_s_setprio(0);
    __builtin_amdgcn_s_barrier();
  }

#pragma unroll
  for (int mf = 0; mf < 4; ++mf) {
    const int grow0 = m0 + wm * 64 + mf * 16 + Lq * 4;
#pragma unroll
    for (int nf = 0; nf < 4; ++nf) {
      const int gcol = n0 + wn * 64 + nf * 16 + L15;
      const float bv = bias[gcol];
#pragma unroll
      for (int r = 0; r < 4; ++r)
        C[(size_t)(grow0 + r) * N + gcol] = acc[mf][nf][r] + bv;
    }
  }
}

// ------------- depthwise causal conv(4) + bias + RoPE, streaming over s -------------
__global__ __launch_bounds__(256) void conv_rope(const u16* __restrict__ qkv,
                                                 const float* __restrict__ cw,
                                                 const float* __restrict__ cb,
                                                 const float* __restrict__ ct,
                                                 const float* __restrict__ st,
                                                 u16* __restrict__ qo,
                                                 u16* __restrict__ ko,
                                                 u16* __restrict__ vtmp) {
  const int blk = blockIdx.x;                 // B * (S/SL)
  const int b = blk >> 7;                     // S/SL = 128
  const int s0 = (blk & 127) * SL;
  const u16* qb = qkv + (size_t)b * S_ * QKV_;

  for (int u = threadIdx.x; u < 896; u += 256) {
    if (u < 640) {
      // ---- rotary unit: features f1,f1+1 and f1+64,f1+65 ----
      const int hs = u >> 5, ip = u & 31, i = ip * 2;
      int f1; u16* outbase; float scale;
      if (hs < 16) {
        f1 = hs * HD + i;
        outbase = qo + (size_t)(b * NH + hs) * S_ * HD;
        scale = 0.08838834764831845f * 1.4426950408889634f;  // log2e/sqrt(128)
      } else {
        f1 = NH * HD + (hs - 16) * HD + i;
        outbase = ko + (size_t)(b * NKV + (hs - 16)) * S_ * HD;
        scale = 1.0f;
      }
      const int f2 = f1 + 64;
      const float4 wA0 = *(const float4*)&cw[f1 * 4];
      const float4 wA1 = *(const float4*)&cw[(f1 + 1) * 4];
      const float4 wB0 = *(const float4*)&cw[f2 * 4];
      const float4 wB1 = *(const float4*)&cw[(f2 + 1) * 4];
      const float cA0 = cb[f1], cA1 = cb[f1 + 1], cB0 = cb[f2], cB1 = cb[f2 + 1];
      float A0[3], A1[3], B0[3], B1[3];
#pragma unroll
      for (int j = 0; j < 3; ++j) {
        const int t = s0 - 3 + j;
        if (t >= 0) {
          const u32 pa = *(const u32*)&qb[(size_t)t * QKV_ + f1];
          const u32 pb = *(const u32*)&qb[(size_t)t * QKV_ + f2];
          A0[j] = bf2f((u16)pa); A1[j] = bf2f((u16)(pa >> 16));
          B0[j] = bf2f((u16)pb); B1[j] = bf2f((u16)(pb >> 16));
        } else { A0[j] = A1[j] = B0[j] = B1[j] = 0.f; }
      }
      for (int s = s0; s < s0 + SL; ++s) {
        const u32 pa = *(const u32*)&qb[(size_t)s * QKV_ + f1];
        const u32 pb = *(const u32*)&qb[(size_t)s * QKV_ + f2];
        const float nA0 = bf2f((u16)pa), nA1 = bf2f((u16)(pa >> 16));
        const float nB0 = bf2f((u16)pb), nB1 = bf2f((u16)(pb >> 16));
        const float x1a = cA0 + wA0.x * A0[0] + wA0.y * A0[1] + wA0.z * A0[2] + wA0.w * nA0;
        const float x1b = cA1 + wA1.x * A1[0] + wA1.y * A1[1] + wA1.z * A1[2] + wA1.w * nA1;
        const float x2a = cB0 + wB0.x * B0[0] + wB0.y * B0[1] + wB0.z * B0[2] + wB0.w * nB0;
        const float x2b = cB1 + wB1.x * B1[0] + wB1.y * B1[1] + wB1.z * B1[2] + wB1.w * nB1;
        const float2 cs = *(const float2*)&ct[s * 64 + i];
        const float2 sn = *(const float2*)&st[s * 64 + i];
        u16* outp = outbase + (size_t)s * HD;
        *(u32*)&outp[i]      = pkbf((x1a * cs.x - x2a * sn.x) * scale,
                                    (x1b * cs.y - x2b * sn.y) * scale);
        *(u32*)&outp[i + 64] = pkbf((x2a * cs.x + x1a * sn.x) * scale,
                                    (x2b * cs.y + x1b * sn.y) * scale);
        A0[0] = A0[1]; A0[1] = A0[2]; A0[2] = nA0;
        A1[0] = A1[1]; A1[1] = A1[2]; A1[2] = nA1;
        B0[0] = B0[1]; B0[1] = B0[2]; B0[2] = nB0;
        B1[0] = B1[1]; B1[1] = B1[2]; B1[2] = nB1;
      }
    } else {
      // ---- v unit: features f, f+1 ----
      const int vu = u - 640, h = vu >> 6, d = (vu & 63) * 2;
      const int f = (NH + NKV) * HD + h * HD + d;
      const float4 w0 = *(const float4*)&cw[f * 4];
      const float4 w1 = *(const float4*)&cw[(f + 1) * 4];
      const float c0 = cb[f], c1 = cb[f + 1];
      float V0[3], V1[3];
#pragma unroll
      for (int j = 0; j < 3; ++j) {
        const int t = s0 - 3 + j;
        if (t >= 0) {
          const u32 p = *(const u32*)&qb[(size_t)t * QKV_ + f];
          V0[j] = bf2f((u16)p); V1[j] = bf2f((u16)(p >> 16));
        } else { V0[j] = V1[j] = 0.f; }
      }
      u16* vrow = vtmp + (size_t)(b * NKV + h) * S_ * HD + d;
      for (int s = s0; s < s0 + SL; ++s) {
        const u32 p = *(const u32*)&qb[(size_t)s * QKV_ + f];
        const float n0 = bf2f((u16)p), n1 = bf2f((u16)(p >> 16));
        const float v0 = c0 + w0.x * V0[0] + w0.y * V0[1] + w0.z * V0[2] + w0.w * n0;
        const float v1 = c1 + w1.x * V1[0] + w1.y * V1[1] + w1.z * V1[2] + w1.w * n1;
        *(u32*)&vrow[(size_t)s * HD] = pkbf(v0, v1);
        V0[0] = V0[1]; V0[1] = V0[2]; V0[2] = n0;
        V1[0] = V1[1]; V1[1] = V1[2]; V1[2] = n1;
      }
    }
  }
}

// ---------------- v (B,NKV,S,HD) -> v^T (B,NKV,HD,S), 64x64 LDS tiles ----------------
// Also resets the attn work-queue counter (runs immediately before attn in-graph).
__global__ __launch_bounds__(256) void vtrans(const u16* __restrict__ vin,
                                              u16* __restrict__ vout,
                                              int* __restrict__ counter) {
  if (blockIdx.x == 0 && blockIdx.y == 0 && blockIdx.z == 0 && threadIdx.x == 0)
    *counter = 0;
  __shared__ u16 t[64][72];
  const int bh = blockIdx.z;
  const int d0 = blockIdx.y * 64;
  const int s0 = blockIdx.x * 64;
  const u16* ip = vin + ((size_t)bh * S_ + s0) * HD + d0;
  const int r = threadIdx.x >> 4, c4 = (threadIdx.x & 15) * 4;
#pragma unroll
  for (int j = 0; j < 4; ++j) {
    const ushort4 v = *(const ushort4*)&ip[(size_t)(r + j * 16) * HD + c4];
    t[c4 + 0][r + j * 16] = v.x;
    t[c4 + 1][r + j * 16] = v.y;
    t[c4 + 2][r + j * 16] = v.z;
    t[c4 + 3][r + j * 16] = v.w;
  }
  __syncthreads();
  const int dl = threadIdx.x >> 2, sc = (threadIdx.x & 3) * 16;
  u16* op = vout + (size_t)bh * HD * S_ + (size_t)(d0 + dl) * S_ + s0 + sc;
  *(bf16x8*)op       = *(const bf16x8*)&t[dl][sc];
  *(bf16x8*)(op + 8) = *(const bf16x8*)&t[dl][sc + 8];
}

// ------------------------- flash attention (causal, GQA) -------------------------
// Round-4 per-tile body (known-good 78 µs) + PERSISTENT-BLOCK WORK QUEUE:
// 768 blocks (3/CU: LDS 48K*3=144K), each loops t=atomicAdd(counter) over 1024
// tasks ordered longest-first (qt = 31 - t/32, bh = t%32). Balance is now
// assignment-independent (round-6 lesson: strided dispatch gave CU i only
// qt==i%32 -> 2x makespan). Swapped QK^T, in-register P, defer-max, counted
// vmcnt(4) mid-barrier.
__global__ __launch_bounds__(256, 3) void attn(const u16* __restrict__ q,
                                               const u16* __restrict__ k,
                                               const u16* __restrict__ v,
                                               u16* __restrict__ ctx,
                                               int* __restrict__ counter) {
  __shared__ u16 Ks[2][64 * 128];
  __shared__ u16 Vs[128 * 64];
  __shared__ int task_s;
  const int tid = threadIdx.x, wave = tid >> 6, lane = tid & 63;
  const int L15 = lane & 15, Lq = lane >> 4;

  const int rx = L15 & 7;
  int koff[4], voff[2];
#pragma unroll
  for (int c = 0; c < 4; ++c) koff[c] = ((c * 4 + Lq) ^ rx) * 8;
#pragma unroll
  for (int kc = 0; kc < 2; ++kc) voff[kc] = ((kc * 4 + Lq) ^ rx) * 8;

  const int ksl = tid >> 4, kcp = tid & 15;
  const int vsl = tid >> 3, vcp = tid & 7;

  // repack geometry: word W of pa[kc] comes from lane (2*(Lq&1)+(W>>1))*16+L15,
  // value w[2kc + (Lq>>1)][W&1]
  const int ls0 = ((Lq & 1) << 5) + L15;
  const int ls1 = ls0 + 16;
  const bool hi = (Lq & 2) != 0;

  for (;;) {
    if (tid == 0) task_s = atomicAdd(counter, 1);
    __syncthreads();
    const int task = task_s;
    if (task >= 32 * 32) break;
    const int qt = 31 - (task >> 5);   // longest-first
    const int bh = task & 31;
    const int b = bh >> 4, h = bh & 15, hk = h >> 2;
    const u16* kb = k + (size_t)(b * NKV + hk) * S_ * HD;
    const u16* vb = v + (size_t)(b * NKV + hk) * HD * S_;
    const int q0 = qt * 64;
    const int base = q0 + wave * 16;

    bf16x8 qf[4];
    {
      const u16* qp = q + ((size_t)bh * S_ + base + L15) * HD + Lq * 8;
#pragma unroll
      for (int c = 0; c < 4; ++c) qf[c] = *(const bf16x8*)(qp + c * 32);
    }

    f32x4 acc[8] = {};
    float m_i = -1e30f, l_i = 0.f;   // per-lane scalars for q = base + L15

    const int ktmax = qt + 1;

    // preamble: stage K(0) and V(0)
#pragma unroll
    for (int j = 0; j < 4; ++j) {
      const int krow = j * 16 + ksl;
      load_lds16(kb + (size_t)krow * HD + (kcp ^ (krow & 7)) * 8,
                 &Ks[0][(krow * 16 + kcp) * 8]);
      const int vrow = j * 32 + vsl;
      load_lds16(vb + (size_t)vrow * S_ + (vcp ^ (vrow & 7)) * 8,
                 &Vs[(vrow * 8 + vcp) * 8]);
    }
    __syncthreads();

    for (int kt = 0; kt < ktmax; ++kt) {
      const int k0 = kt * 64;
      const int cur = kt & 1;
      if (kt > 0) {  // V(kt): buffer free since end-barrier of kt-1
#pragma unroll
        for (int j = 0; j < 4; ++j) {
          const int vrow = j * 32 + vsl;
          load_lds16(vb + (size_t)vrow * S_ + k0 + (vcp ^ (vrow & 7)) * 8,
                     &Vs[(vrow * 8 + vcp) * 8]);
        }
      }
      if (kt + 1 < ktmax) {  // K(kt+1) into other K buffer
        const int kn = k0 + 64;
#pragma unroll
        for (int j = 0; j < 4; ++j) {
          const int krow = j * 16 + ksl;
          load_lds16(kb + (size_t)(kn + krow) * HD + (kcp ^ (krow & 7)) * 8,
                     &Ks[cur ^ 1][(krow * 16 + kcp) * 8]);
        }
      }
      // ---- swapped QK^T: sc[nt][r] = S[q=base+L15][k=k0+nt*16+Lq*4+r] ----
      f32x4 sc[4];
#pragma unroll
      for (int nt = 0; nt < 4; ++nt) sc[nt] = f32x4{0.f, 0.f, 0.f, 0.f};
#pragma unroll
      for (int nt = 0; nt < 4; ++nt) {
#pragma unroll
        for (int c = 0; c < 4; ++c) {
          const bf16x8 kf = *(const bf16x8*)&Ks[cur][(nt * 16 + L15) * 128 + koff[c]];
          sc[nt] = __builtin_amdgcn_mfma_f32_16x16x32_bf16(kf, qf[c], sc[nt], 0, 0, 0);
        }
      }
      if (k0 + 63 > base) {  // diagonal tile: causal mask
#pragma unroll
        for (int nt = 0; nt < 4; ++nt)
#pragma unroll
          for (int r = 0; r < 4; ++r) {
            const int kidx = k0 + nt * 16 + Lq * 4 + r;
            if (kidx > base + L15) sc[nt][r] = -1e30f;
          }
      }
      // ---- row max (in-lane tree + 2 shfl) ----
      float mloc = fmaxf(fmaxf(fmaxf(sc[0][0], sc[0][1]), fmaxf(sc[0][2], sc[0][3])),
                         fmaxf(fmaxf(sc[1][0], sc[1][1]), fmaxf(sc[1][2], sc[1][3])));
      mloc = fmaxf(mloc,
                   fmaxf(fmaxf(fmaxf(sc[2][0], sc[2][1]), fmaxf(sc[2][2], sc[2][3])),
                         fmaxf(fmaxf(sc[3][0], sc[3][1]), fmaxf(sc[3][2], sc[3][3]))));
      mloc = fmaxf(mloc, __shfl_xor(mloc, 16));
      mloc = fmaxf(mloc, __shfl_xor(mloc, 32));
      // ---- defer-max online update ----
      const bool defer = __all(mloc - m_i <= 8.f);
      if (!defer) {
        const float mnew = fmaxf(m_i, mloc);
        const float alpha = ex2(m_i - mnew);
        m_i = mnew;
        l_i *= alpha;
        float aacc[4];
#pragma unroll
        for (int r = 0; r < 4; ++r) aacc[r] = __shfl(alpha, Lq * 4 + r);
#pragma unroll
        for (int dt = 0; dt < 8; ++dt)
#pragma unroll
          for (int r = 0; r < 4; ++r) acc[dt][r] *= aacc[r];
      }
      // ---- P = exp2(S - m), row sum ----
      float lsum = 0.f;
#pragma unroll
      for (int nt = 0; nt < 4; ++nt)
#pragma unroll
        for (int r = 0; r < 4; ++r) {
          sc[nt][r] = ex2(sc[nt][r] - m_i);
          lsum += sc[nt][r];
        }
      lsum += __shfl_xor(lsum, 16);
      lsum += __shfl_xor(lsum, 32);
      l_i += lsum;
      // ---- pack P pairs: w[nt][j] = k = nt*16 + Lq*4 + 2j + {0,1} ----
      u32 wA[2], wB[2], wC[2], wD[2];
      wA[0] = pkbf(sc[0][0], sc[0][1]); wA[1] = pkbf(sc[0][2], sc[0][3]);
      wB[0] = pkbf(sc[1][0], sc[1][1]); wB[1] = pkbf(sc[1][2], sc[1][3]);
      wC[0] = pkbf(sc[2][0], sc[2][1]); wC[1] = pkbf(sc[2][2], sc[2][3]);
      wD[0] = pkbf(sc[3][0], sc[3][1]); wD[1] = pkbf(sc[3][2], sc[3][3]);
      // ---- cross-lane repack -> pa[kc] = P[q=L15][k=kc*32+Lq*8+e] ----
      bf16x8 pa[2];
      {
        union { u32 u[4]; bf16x8 v; } t0, t1;
        u32 x0, x1;
        x0 = shf(wA[0], ls0); x1 = shf(wB[0], ls0); t0.u[0] = hi ? x1 : x0;
        x0 = shf(wA[1], ls0); x1 = shf(wB[1], ls0); t0.u[1] = hi ? x1 : x0;
        x0 = shf(wA[0], ls1); x1 = shf(wB[0], ls1); t0.u[2] = hi ? x1 : x0;
        x0 = shf(wA[1], ls1); x1 = shf(wB[1], ls1); t0.u[3] = hi ? x1 : x0;
        x0 = shf(wC[0], ls0); x1 = shf(wD[0], ls0); t1.u[0] = hi ? x1 : x0;
        x0 = shf(wC[1], ls0); x1 = shf(wD[1], ls0); t1.u[1] = hi ? x1 : x0;
        x0 = shf(wC[0], ls1); x1 = shf(wD[0], ls1); t1.u[2] = hi ? x1 : x0;
        x0 = shf(wC[1], ls1); x1 = shf(wD[1], ls1); t1.u[3] = hi ? x1 : x0;
        pa[0] = t0.v; pa[1] = t1.v;
      }
      // ---- M barrier: retire V(kt) only; K(kt+1) stays in flight ----
      if (kt + 1 < ktmax) asm volatile("s_waitcnt vmcnt(4)" ::: "memory");
      else                asm volatile("s_waitcnt vmcnt(0)" ::: "memory");
      __builtin_amdgcn_s_barrier();
      asm volatile("" ::: "memory");
      // ---- PV from Vs ----
#pragma unroll
      for (int dt = 0; dt < 8; ++dt)
#pragma unroll
        for (int kc = 0; kc < 2; ++kc) {
          const bf16x8 vf = *(const bf16x8*)&Vs[(dt * 16 + L15) * 64 + voff[kc]];
          acc[dt] = __builtin_amdgcn_mfma_f32_16x16x32_bf16(pa[kc], vf, acc[dt], 0, 0, 0);
        }
      __syncthreads();  // E: V reads done + K(kt+1) drained before next iter
    }
    // ---- epilogue ----
    {
      float inv[4];
#pragma unroll
      for (int r = 0; r < 4; ++r) inv[r] = 1.f / __shfl(l_i, Lq * 4 + r);
      u16* cp = ctx + ((size_t)b * S_ + base) * (NH * HD) + h * HD;
#pragma unroll
      for (int dt = 0; dt < 8; ++dt)
#pragma unroll
        for (int rp = 0; rp < 2; ++rp) {
          const u32 pk = pkbf(acc[dt][rp * 2] * inv[rp * 2],
                              acc[dt][rp * 2 + 1] * inv[rp * 2 + 1]);
          cp[(size_t)(Lq * 4 + rp * 2) * (NH * HD) + dt * 16 + L15] = (u16)pk;
          cp[(size_t)(Lq * 4 + rp * 2 + 1) * (NH * HD) + dt * 16 + L15] = (u16)(pk >> 16);
        }
    }
  }
}

extern "C" void kernel_launch(void* const* d_in, const int* in_sizes, int n_in,
                              void* d_out, int out_size, void* d_ws, size_t ws_size,
                              hipStream_t stream) {
  const float* x     = (const float*)d_in[0];
  const float* W_in  = (const float*)d_in[1];
  const float* b_in  = (const float*)d_in[2];
  const float* cw    = (const float*)d_in[3];
  const float* cb    = (const float*)d_in[4];
  const float* W_out = (const float*)d_in[5];
  const float* b_out = (const float*)d_in[6];

  char* ws = (char*)d_ws;
  u16* xb   = (u16*)(ws);                    // 16777216 B (dead after gemm1)
  u16* wib  = (u16*)(ws + 16777216);         // 12582912 B (dead after gemm1)
  u16* wob  = (u16*)(ws + 29360128);         //  8388608 B
  u16* qkv  = (u16*)(ws + 37748736);         // 25165824 B
  u16* q_ws = (u16*)(ws + 62914560);         // 16777216 B
  u16* k_ws = (u16*)(ws + 79691776);         //  4194304 B
  u16* vt_ws= (u16*)(ws + 83886080);         //  4194304 B
  float* ctab = (float*)ws;                  // rope tables in dead xb region
  float* stab = (float*)(ws + 524288);
  u16* vtmp = wib;                           // v row-major, in dead wib region
  u16* ctx  = xb;                            // alias: xb dead after gemm1
  int* counter = (int*)(ws + 16777216 + 4194304);  // dead wib region, after vtmp

  const int nx = B_ * S_ * E_ / 4, nwi = QKV_ * E_ / 4, nwo = E_ * NH * HD / 4;
  f2b_conv<<<dim3((nx  + 255) / 256), 256, 0, stream>>>(x,     xb,  nx);
  f2b_conv<<<dim3((nwi + 255) / 256), 256, 0, stream>>>(W_in,  wib, nwi);
  f2b_conv<<<dim3((nwo + 255) / 256), 256, 0, stream>>>(W_out, wob, nwo);

  gemm256<1><<<dim3(QKV_ / 256, (B_ * S_) / 256), 512, 0, stream>>>(
      xb, wib, b_in, (void*)qkv, B_ * S_, QKV_, E_);
  rope_tab<<<dim3(S_ * 64 / 256), 256, 0, stream>>>(ctab, stab);
  conv_rope<<<dim3(B_ * (S_ / SL)), 256, 0, stream>>>(qkv, cw, cb, ctab, stab, q_ws, k_ws, vtmp);
  vtrans<<<dim3(S_ / 64, HD / 64, B_ * NKV), 256, 0, stream>>>(vtmp, vt_ws, counter);
  attn<<<dim3(768), 256, 0, stream>>>(q_ws, k_ws, vt_ws, ctx, counter);
  gemm_n128<<<dim3(E_ / 128, (B_ * S_) / 256), 512, 0, stream>>>(
      ctx, wob, b_out, (float*)d_out, B_ * S_, E_, NH * HD);
}

// Round 10
// 323.932 us; speedup vs baseline: 1.1512x; 1.0255x over previous
//
#include <hip/hip_runtime.h>
#include <hip/hip_bf16.h>

#define B_   2
#define S_   2048
#define E_   2048
#define QKV_ 3072
#define NH   16
#define NKV  4
#define HD   128
#define SL   16   // conv_rope strip length

typedef __attribute__((ext_vector_type(8))) short bf16x8;
typedef __attribute__((ext_vector_type(4))) float f32x4;
typedef unsigned short u16;
typedef unsigned int   u32;

__device__ __forceinline__ float bf2f(u16 u) {
  union { u32 i; float f; } v; v.i = ((u32)u) << 16; return v.f;
}
__device__ __forceinline__ u16 f2bf(float f) {
  union { float f; u32 u; } v; v.f = f;
  return (u16)((v.u + 0x7FFFu + ((v.u >> 16) & 1u)) >> 16);
}
__device__ __forceinline__ u32 pkbf(float a, float b) {
  __hip_bfloat162 h = __float22bfloat162_rn(float2{a, b});
  u32 r; __builtin_memcpy(&r, &h, 4); return r;
}
__device__ __forceinline__ float ex2(float x) { return __builtin_amdgcn_exp2f(x); }
__device__ __forceinline__ u32 shf(u32 v, int l) { return (u32)__shfl((int)v, l); }
__device__ __forceinline__ void load_lds16(const u16* g, u16* l) {
  __builtin_amdgcn_global_load_lds((const __attribute__((address_space(1))) void*)g,
                                   (__attribute__((address_space(3))) void*)l, 16, 0, 0);
}

// ------- fused fp32 -> bf16 bulk convert for x, W_in, W_out (one launch) -------
// float4 counts: nx=2097152, nwi=1572864, nwo=1048576 (all multiples of 256 ->
// range branches are wave-uniform).
__global__ __launch_bounds__(256) void f2b3(const float* __restrict__ x,
                                            const float* __restrict__ wi,
                                            const float* __restrict__ wo,
                                            u16* __restrict__ xb,
                                            u16* __restrict__ wib,
                                            u16* __restrict__ wob) {
  const int i = blockIdx.x * 256 + threadIdx.x;
  const float* src; u16* dst; int j;
  if (i < 2097152)            { src = x;  dst = xb;  j = i; }
  else if (i < 2097152 + 1572864) { src = wi; dst = wib; j = i - 2097152; }
  else                        { src = wo; dst = wob; j = i - 3670016; }
  const float4 v = ((const float4*)src)[j];
  ushort4 o;
  o.x = f2bf(v.x); o.y = f2bf(v.y); o.z = f2bf(v.z); o.w = f2bf(v.w);
  ((ushort4*)dst)[j] = o;
}

// ------------- 256x256 8-phase GEMM: C[M,N] = A[M,K]*B[N,K]^T + bias[N] -------------
// (unchanged — see round-3 comments for the schedule proof)
template <int OUT_BF16>
__global__ __launch_bounds__(512, 2) void gemm256(const u16* __restrict__ A,
                                                  const u16* __restrict__ Bm,
                                                  const float* __restrict__ bias,
                                                  void* __restrict__ C,
                                                  int M, int N, int K) {
  __shared__ u16 sm[2][2][256 * 64];   // [buf][0=A,1=B][row*64 + unit*8 + e]
  const int tid = threadIdx.x;
  const int lane = tid & 63;
  const int wave = tid >> 6;
  const int wm = wave >> 2, wn = wave & 3;
  const int L15 = lane & 15, Lq = lane >> 4;
  const int m0 = blockIdx.y * 256, n0 = blockIdx.x * 256;
  const int NT = K >> 6;

  const int srow = tid >> 3;
  const int sdst = (tid & 7) * 8;
  const int ssrc = ((tid & 7) ^ (srow & 7)) * 8;

  auto stageA = [&](int T, int h, int j) {
    const int row = h * 128 + j * 64 + srow;
    load_lds16(A + (size_t)(m0 + row) * K + T * 64 + ssrc,
               &sm[T & 1][0][row * 64 + sdst]);
  };
  auto stageB = [&](int T, int h, int j) {
    const int row = h * 128 + j * 64 + srow;
    load_lds16(Bm + (size_t)(n0 + row) * K + T * 64 + ssrc,
               &sm[T & 1][1][row * 64 + sdst]);
  };
  auto rdA = [&](int p, int ms, int mf, int kk) -> bf16x8 {
    const int row = wm * 128 + ms * 64 + mf * 16 + L15;
    const int u = (kk * 4 + Lq) ^ (row & 7);
    return *(const bf16x8*)&sm[p][0][row * 64 + u * 8];
  };
  auto rdB = [&](int p, int ns, int nf, int kk) -> bf16x8 {
    const int row = wn * 64 + ns * 32 + nf * 16 + L15;
    const int u = (kk * 4 + Lq) ^ (row & 7);
    return *(const bf16x8*)&sm[p][1][row * 64 + u * 8];
  };

  f32x4 acc[8][4] = {};

  stageA(0, 0, 0); stageA(0, 0, 1);
  stageB(0, 0, 0); stageB(0, 0, 1);
  stageA(0, 1, 0); stageA(0, 1, 1);
  stageB(0, 1, 0); stageB(0, 1, 1);
  stageB(1, 0, 0); stageB(1, 0, 1);
  stageA(1, 0, 0); stageA(1, 0, 1);
  asm volatile("s_waitcnt vmcnt(4)" ::: "memory");
  __builtin_amdgcn_s_barrier();

  bf16x8 af[4][2], bf0[2][2], bf1[2][2];

#define MFMA_QUAD(MS, NS, BF)                                                     \
  __builtin_amdgcn_s_setprio(1);                                                  \
  _Pragma("unroll")                                                               \
  for (int kk = 0; kk < 2; ++kk)                                                  \
    _Pragma("unroll")                                                             \
    for (int mf = 0; mf < 4; ++mf)                                                \
      _Pragma("unroll")                                                           \
      for (int nf = 0; nf < 2; ++nf)                                              \
        acc[MS * 4 + mf][NS * 2 + nf] = __builtin_amdgcn_mfma_f32_16x16x32_bf16(  \
            af[mf][kk], BF[nf][kk], acc[MS * 4 + mf][NS * 2 + nf], 0, 0, 0);      \
  __builtin_amdgcn_s_setprio(0);

  for (int T = 0; T < NT; ++T) {
    const int p = T & 1;
#pragma unroll
    for (int mf = 0; mf < 4; ++mf)
#pragma unroll
      for (int kk = 0; kk < 2; ++kk) af[mf][kk] = rdA(p, 0, mf, kk);
#pragma unroll
    for (int nf = 0; nf < 2; ++nf)
#pragma unroll
      for (int kk = 0; kk < 2; ++kk) bf0[nf][kk] = rdB(p, 0, nf, kk);
    if (T + 1 < NT) { stageA(T + 1, 1, 0); stageA(T + 1, 1, 1); }
    __builtin_amdgcn_s_barrier();
    MFMA_QUAD(0, 0, bf0)
    __builtin_amdgcn_s_barrier();
#pragma unroll
    for (int nf = 0; nf < 2; ++nf)
#pragma unroll
      for (int kk = 0; kk < 2; ++kk) bf1[nf][kk] = rdB(p, 1, nf, kk);
    if (T + 1 < NT) { stageB(T + 1, 1, 0); stageB(T + 1, 1, 1); }
    __builtin_amdgcn_s_barrier();
    MFMA_QUAD(0, 1, bf1)
    __builtin_amdgcn_s_barrier();
#pragma unroll
    for (int mf = 0; mf < 4; ++mf)
#pragma unroll
      for (int kk = 0; kk < 2; ++kk) af[mf][kk] = rdA(p, 1, mf, kk);
    if (T + 2 < NT) { stageB(T + 2, 0, 0); stageB(T + 2, 0, 1); }
    __builtin_amdgcn_s_barrier();
    MFMA_QUAD(1, 0, bf0)
    __builtin_amdgcn_s_barrier();
    if (T + 2 < NT) {
      stageA(T + 2, 0, 0); stageA(T + 2, 0, 1);
      asm volatile("s_waitcnt vmcnt(4)" ::: "memory");
    } else {
      asm volatile("s_waitcnt vmcnt(0)" ::: "memory");
    }
    __builtin_amdgcn_s_barrier();
    MFMA_QUAD(1, 1, bf1)
    __builtin_amdgcn_s_barrier();
  }
#undef MFMA_QUAD

#pragma unroll
  for (int ms = 0; ms < 2; ++ms)
#pragma unroll
    for (int mf = 0; mf < 4; ++mf) {
      const int grow0 = m0 + wm * 128 + ms * 64 + mf * 16 + Lq * 4;
#pragma unroll
      for (int ns = 0; ns < 2; ++ns)
#pragma unroll
        for (int nf = 0; nf < 2; ++nf) {
          const int gcol = n0 + wn * 64 + ns * 32 + nf * 16 + L15;
          const float bv = bias[gcol];
          const f32x4 v = acc[ms * 4 + mf][ns * 2 + nf];
#pragma unroll
          for (int r = 0; r < 4; ++r) {
            const float o = v[r] + bv;
            if (OUT_BF16) ((u16*)C)[(size_t)(grow0 + r) * N + gcol] = f2bf(o);
            else          ((float*)C)[(size_t)(grow0 + r) * N + gcol] = o;
          }
        }
    }
}

// ------------- 256x128 GEMM (grid-filling variant for N=2048): C = A*B^T + bias ----
// (unchanged)
__global__ __launch_bounds__(512, 2) void gemm_n128(const u16* __restrict__ A,
                                                    const u16* __restrict__ Bm,
                                                    const float* __restrict__ bias,
                                                    float* __restrict__ C,
                                                    int M, int N, int K) {
  __shared__ u16 sm[2][24576];  // [buf][ A 256*64 | B 128*64 ]
  const int tid = threadIdx.x, lane = tid & 63, wave = tid >> 6;
  const int wm = wave >> 1, wn = wave & 1;
  const int L15 = lane & 15, Lq = lane >> 4;
  const int m0 = blockIdx.y * 256, n0 = blockIdx.x * 128;
  const int NT = K >> 6;

  const int srow = tid >> 3;
  const int sdst = (tid & 7) * 8;
  const int ssrc = ((tid & 7) ^ (srow & 7)) * 8;

  auto stage6 = [&](int T) {
#pragma unroll
    for (int c = 0; c < 4; ++c) {
      const int row = c * 64 + srow;
      load_lds16(A + (size_t)(m0 + row) * K + T * 64 + ssrc,
                 &sm[T & 1][row * 64 + sdst]);
    }
#pragma unroll
    for (int c = 0; c < 2; ++c) {
      const int row = c * 64 + srow;
      load_lds16(Bm + (size_t)(n0 + row) * K + T * 64 + ssrc,
                 &sm[T & 1][16384 + row * 64 + sdst]);
    }
  };

  f32x4 acc[4][4] = {};
  stage6(0);

  for (int T = 0; T < NT; ++T) {
    const int p = T & 1;
    if (T + 1 < NT) {
      stage6(T + 1);
      asm volatile("s_waitcnt vmcnt(6)" ::: "memory");
    } else {
      asm volatile("s_waitcnt vmcnt(0)" ::: "memory");
    }
    __builtin_amdgcn_s_barrier();
    bf16x8 af[4][2], bfr[4][2];
#pragma unroll
    for (int mf = 0; mf < 4; ++mf)
#pragma unroll
      for (int kk = 0; kk < 2; ++kk) {
        const int row = wm * 64 + mf * 16 + L15;
        const int u = (kk * 4 + Lq) ^ (row & 7);
        af[mf][kk] = *(const bf16x8*)&sm[p][row * 64 + u * 8];
      }
#pragma unroll
    for (int nf = 0; nf < 4; ++nf)
#pragma unroll
      for (int kk = 0; kk < 2; ++kk) {
        const int row = wn * 64 + nf * 16 + L15;
        const int u = (kk * 4 + Lq) ^ (row & 7);
        bfr[nf][kk] = *(const bf16x8*)&sm[p][16384 + row * 64 + u * 8];
      }
    __builtin_amdgcn_s_setprio(1);
#pragma unroll
    for (int kk = 0; kk < 2; ++kk)
#pragma unroll
      for (int mf = 0; mf < 4; ++mf)
#pragma unroll
        for (int nf = 0; nf < 4; ++nf)
          acc[mf][nf] = __builtin_amdgcn_mfma_f32_16x16x32_bf16(
              af[mf][kk], bfr[nf][kk], acc[mf][nf], 0, 0, 0);
    __builtin_amdgcn_s_setprio(0);
    __builtin_amdgcn_s_barrier();
  }

#pragma unroll
  for (int mf = 0; mf < 4; ++mf) {
    const int grow0 = m0 + wm * 64 + mf * 16 + Lq * 4;
#pragma unroll
    for (int nf = 0; nf < 4; ++nf) {
      const int gcol = n0 + wn * 64 + nf * 16 + L15;
      const float bv = bias[gcol];
#pragma unroll
      for (int r = 0; r < 4; ++r)
        C[(size_t)(grow0 + r) * N + gcol] = acc[mf][nf][r] + bv;
    }
  }
}

// ------------- depthwise causal conv(4) + bias + RoPE, streaming over s -------------
// rope_tab folded in: cos/sin computed inline per unit (identical powf/sincosf
// expressions as the old table kernel -> identical numerics), one less launch.
__global__ __launch_bounds__(256) void conv_rope(const u16* __restrict__ qkv,
                                                 const float* __restrict__ cw,
                                                 const float* __restrict__ cb,
                                                 u16* __restrict__ qo,
                                                 u16* __restrict__ ko,
                                                 u16* __restrict__ vtmp) {
  const int blk = blockIdx.x;                 // B * (S/SL)
  const int b = blk >> 7;                     // S/SL = 128
  const int s0 = (blk & 127) * SL;
  const u16* qb = qkv + (size_t)b * S_ * QKV_;

  for (int u = threadIdx.x; u < 896; u += 256) {
    if (u < 640) {
      // ---- rotary unit: features f1,f1+1 and f1+64,f1+65 ----
      const int hs = u >> 5, ip = u & 31, i = ip * 2;
      int f1; u16* outbase; float scale;
      if (hs < 16) {
        f1 = hs * HD + i;
        outbase = qo + (size_t)(b * NH + hs) * S_ * HD;
        scale = 0.08838834764831845f * 1.4426950408889634f;  // log2e/sqrt(128)
      } else {
        f1 = NH * HD + (hs - 16) * HD + i;
        outbase = ko + (size_t)(b * NKV + (hs - 16)) * S_ * HD;
        scale = 1.0f;
      }
      const float invf0 = powf(10000.0f, -(float)i * (1.0f / 64.0f));
      const float invf1 = powf(10000.0f, -(float)(i + 1) * (1.0f / 64.0f));
      const int f2 = f1 + 64;
      const float4 wA0 = *(const float4*)&cw[f1 * 4];
      const float4 wA1 = *(const float4*)&cw[(f1 + 1) * 4];
      const float4 wB0 = *(const float4*)&cw[f2 * 4];
      const float4 wB1 = *(const float4*)&cw[(f2 + 1) * 4];
      const float cA0 = cb[f1], cA1 = cb[f1 + 1], cB0 = cb[f2], cB1 = cb[f2 + 1];
      float A0[3], A1[3], B0[3], B1[3];
#pragma unroll
      for (int j = 0; j < 3; ++j) {
        const int t = s0 - 3 + j;
        if (t >= 0) {
          const u32 pa = *(const u32*)&qb[(size_t)t * QKV_ + f1];
          const u32 pb = *(const u32*)&qb[(size_t)t * QKV_ + f2];
          A0[j] = bf2f((u16)pa); A1[j] = bf2f((u16)(pa >> 16));
          B0[j] = bf2f((u16)pb); B1[j] = bf2f((u16)(pb >> 16));
        } else { A0[j] = A1[j] = B0[j] = B1[j] = 0.f; }
      }
      for (int s = s0; s < s0 + SL; ++s) {
        const u32 pa = *(const u32*)&qb[(size_t)s * QKV_ + f1];
        const u32 pb = *(const u32*)&qb[(size_t)s * QKV_ + f2];
        const float nA0 = bf2f((u16)pa), nA1 = bf2f((u16)(pa >> 16));
        const float nB0 = bf2f((u16)pb), nB1 = bf2f((u16)(pb >> 16));
        const float x1a = cA0 + wA0.x * A0[0] + wA0.y * A0[1] + wA0.z * A0[2] + wA0.w * nA0;
        const float x1b = cA1 + wA1.x * A1[0] + wA1.y * A1[1] + wA1.z * A1[2] + wA1.w * nA1;
        const float x2a = cB0 + wB0.x * B0[0] + wB0.y * B0[1] + wB0.z * B0[2] + wB0.w * nB0;
        const float x2b = cB1 + wB1.x * B1[0] + wB1.y * B1[1] + wB1.z * B1[2] + wB1.w * nB1;
        float sn0, cs0, sn1, cs1;
        sincosf((float)s * invf0, &sn0, &cs0);
        sincosf((float)s * invf1, &sn1, &cs1);
        u16* outp = outbase + (size_t)s * HD;
        *(u32*)&outp[i]      = pkbf((x1a * cs0 - x2a * sn0) * scale,
                                    (x1b * cs1 - x2b * sn1) * scale);
        *(u32*)&outp[i + 64] = pkbf((x2a * cs0 + x1a * sn0) * scale,
                                    (x2b * cs1 + x1b * sn1) * scale);
        A0[0] = A0[1]; A0[1] = A0[2]; A0[2] = nA0;
        A1[0] = A1[1]; A1[1] = A1[2]; A1[2] = nA1;
        B0[0] = B0[1]; B0[1] = B0[2]; B0[2] = nB0;
        B1[0] = B1[1]; B1[1] = B1[2]; B1[2] = nB1;
      }
    } else {
      // ---- v unit: features f, f+1 ----
      const int vu = u - 640, h = vu >> 6, d = (vu & 63) * 2;
      const int f = (NH + NKV) * HD + h * HD + d;
      const float4 w0 = *(const float4*)&cw[f * 4];
      const float4 w1 = *(const float4*)&cw[(f + 1) * 4];
      const float c0 = cb[f], c1 = cb[f + 1];
      float V0[3], V1[3];
#pragma unroll
      for (int j = 0; j < 3; ++j) {
        const int t = s0 - 3 + j;
        if (t >= 0) {
          const u32 p = *(const u32*)&qb[(size_t)t * QKV_ + f];
          V0[j] = bf2f((u16)p); V1[j] = bf2f((u16)(p >> 16));
        } else { V0[j] = V1[j] = 0.f; }
      }
      u16* vrow = vtmp + (size_t)(b * NKV + h) * S_ * HD + d;
      for (int s = s0; s < s0 + SL; ++s) {
        const u32 p = *(const u32*)&qb[(size_t)s * QKV_ + f];
        const float n0 = bf2f((u16)p), n1 = bf2f((u16)(p >> 16));
        const float v0 = c0 + w0.x * V0[0] + w0.y * V0[1] + w0.z * V0[2] + w0.w * n0;
        const float v1 = c1 + w1.x * V1[0] + w1.y * V1[1] + w1.z * V1[2] + w1.w * n1;
        *(u32*)&vrow[(size_t)s * HD] = pkbf(v0, v1);
        V0[0] = V0[1]; V0[1] = V0[2]; V0[2] = n0;
        V1[0] = V1[1]; V1[1] = V1[2]; V1[2] = n1;
      }
    }
  }
}

// ---------------- v (B,NKV,S,HD) -> v^T (B,NKV,HD,S), 64x64 LDS tiles ----------------
__global__ __launch_bounds__(256) void vtrans(const u16* __restrict__ vin,
                                              u16* __restrict__ vout) {
  __shared__ u16 t[64][72];
  const int bh = blockIdx.z;
  const int d0 = blockIdx.y * 64;
  const int s0 = blockIdx.x * 64;
  const u16* ip = vin + ((size_t)bh * S_ + s0) * HD + d0;
  const int r = threadIdx.x >> 4, c4 = (threadIdx.x & 15) * 4;
#pragma unroll
  for (int j = 0; j < 4; ++j) {
    const ushort4 v = *(const ushort4*)&ip[(size_t)(r + j * 16) * HD + c4];
    t[c4 + 0][r + j * 16] = v.x;
    t[c4 + 1][r + j * 16] = v.y;
    t[c4 + 2][r + j * 16] = v.z;
    t[c4 + 3][r + j * 16] = v.w;
  }
  __syncthreads();
  const int dl = threadIdx.x >> 2, sc = (threadIdx.x & 3) * 16;
  u16* op = vout + (size_t)bh * HD * S_ + (size_t)(d0 + dl) * S_ + s0 + sc;
  *(bf16x8*)op       = *(const bf16x8*)&t[dl][sc];
  *(bf16x8*)(op + 8) = *(const bf16x8*)&t[dl][sc + 8];
}

// ------------------------- flash attention (causal, GQA) -------------------------
// EXACT round-4 kernel (best measured: 78 µs). 64-row q-tiles, grid (16, B*NH) =
// 512 blocks, 2 blocks/CU; block i does qt=i and qt=31-i (33 balanced k-iters).
// Swapped QK^T (full q-row per lane), in-register P repack, defer-max, counted
// vmcnt(4) mid-barrier (K(kt+1) stays in flight). LDS 48 KB.
// Schedule experiments r5 (single-barrier V-dbuf), r6 (unpaired grid), r7
// (persistent queue) all regressed — do not touch.
__global__ __launch_bounds__(256, 2) void attn(const u16* __restrict__ q,
                                               const u16* __restrict__ k,
                                               const u16* __restrict__ v,
                                               u16* __restrict__ ctx) {
  __shared__ u16 Ks[2][64 * 128];
  __shared__ u16 Vs[128 * 64];
  const int tid = threadIdx.x, wave = tid >> 6, lane = tid & 63;
  const int L15 = lane & 15, Lq = lane >> 4;
  const int bh = blockIdx.y;
  const int b = bh >> 4, h = bh & 15, hk = h >> 2;

  const u16* kb = k + (size_t)(b * NKV + hk) * S_ * HD;
  const u16* vb = v + (size_t)(b * NKV + hk) * HD * S_;

  const int rx = L15 & 7;
  int koff[4], voff[2];
#pragma unroll
  for (int c = 0; c < 4; ++c) koff[c] = ((c * 4 + Lq) ^ rx) * 8;
#pragma unroll
  for (int kc = 0; kc < 2; ++kc) voff[kc] = ((kc * 4 + Lq) ^ rx) * 8;

  const int ksl = tid >> 4, kcp = tid & 15;
  const int vsl = tid >> 3, vcp = tid & 7;

  const int ls0 = ((Lq & 1) << 5) + L15;
  const int ls1 = ls0 + 16;
  const bool hi = (Lq & 2) != 0;

  for (int pass = 0; pass < 2; ++pass) {
    const int qt = pass ? (31 - blockIdx.x) : blockIdx.x;
    const int q0 = qt * 64;
    const int base = q0 + wave * 16;

    bf16x8 qf[4];
    {
      const u16* qp = q + ((size_t)bh * S_ + base + L15) * HD + Lq * 8;
#pragma unroll
      for (int c = 0; c < 4; ++c) qf[c] = *(const bf16x8*)(qp + c * 32);
    }

    f32x4 acc[8] = {};
    float m_i = -1e30f, l_i = 0.f;   // per-lane scalars for q = base + L15

    const int ktmax = qt + 1;

    // preamble: stage K(0) and V(0)
#pragma unroll
    for (int j = 0; j < 4; ++j) {
      const int krow = j * 16 + ksl;
      load_lds16(kb + (size_t)krow * HD + (kcp ^ (krow & 7)) * 8,
                 &Ks[0][(krow * 16 + kcp) * 8]);
      const int vrow = j * 32 + vsl;
      load_lds16(vb + (size_t)vrow * S_ + (vcp ^ (vrow & 7)) * 8,
                 &Vs[(vrow * 8 + vcp) * 8]);
    }
    __syncthreads();

    for (int kt = 0; kt < ktmax; ++kt) {
      const int k0 = kt * 64;
      const int cur = kt & 1;
      if (kt > 0) {  // V(kt): buffer free since end-barrier of kt-1
#pragma unroll
        for (int j = 0; j < 4; ++j) {
          const int vrow = j * 32 + vsl;
          load_lds16(vb + (size_t)vrow * S_ + k0 + (vcp ^ (vrow & 7)) * 8,
                     &Vs[(vrow * 8 + vcp) * 8]);
        }
      }
      if (kt + 1 < ktmax) {  // K(kt+1) into other K buffer
        const int kn = k0 + 64;
#pragma unroll
        for (int j = 0; j < 4; ++j) {
          const int krow = j * 16 + ksl;
          load_lds16(kb + (size_t)(kn + krow) * HD + (kcp ^ (krow & 7)) * 8,
                     &Ks[cur ^ 1][(krow * 16 + kcp) * 8]);
        }
      }
      // ---- swapped QK^T: sc[nt][r] = S[q=base+L15][k=k0+nt*16+Lq*4+r] ----
      f32x4 sc[4];
#pragma unroll
      for (int nt = 0; nt < 4; ++nt) sc[nt] = f32x4{0.f, 0.f, 0.f, 0.f};
#pragma unroll
      for (int nt = 0; nt < 4; ++nt) {
#pragma unroll
        for (int c = 0; c < 4; ++c) {
          const bf16x8 kf = *(const bf16x8*)&Ks[cur][(nt * 16 + L15) * 128 + koff[c]];
          sc[nt] = __builtin_amdgcn_mfma_f32_16x16x32_bf16(kf, qf[c], sc[nt], 0, 0, 0);
        }
      }
      if (k0 + 63 > base) {  // diagonal tile: causal mask
#pragma unroll
        for (int nt = 0; nt < 4; ++nt)
#pragma unroll
          for (int r = 0; r < 4; ++r) {
            const int kidx = k0 + nt * 16 + Lq * 4 + r;
            if (kidx > base + L15) sc[nt][r] = -1e30f;
          }
      }
      // ---- row max (in-lane tree + 2 shfl) ----
      float mloc = fmaxf(fmaxf(fmaxf(sc[0][0], sc[0][1]), fmaxf(sc[0][2], sc[0][3])),
                         fmaxf(fmaxf(sc[1][0], sc[1][1]), fmaxf(sc[1][2], sc[1][3])));
      mloc = fmaxf(mloc,
                   fmaxf(fmaxf(fmaxf(sc[2][0], sc[2][1]), fmaxf(sc[2][2], sc[2][3])),
                         fmaxf(fmaxf(sc[3][0], sc[3][1]), fmaxf(sc[3][2], sc[3][3]))));
      mloc = fmaxf(mloc, __shfl_xor(mloc, 16));
      mloc = fmaxf(mloc, __shfl_xor(mloc, 32));
      // ---- defer-max online update ----
      const bool defer = __all(mloc - m_i <= 8.f);
      if (!defer) {
        const float mnew = fmaxf(m_i, mloc);
        const float alpha = ex2(m_i - mnew);
        m_i = mnew;
        l_i *= alpha;
        float aacc[4];
#pragma unroll
        for (int r = 0; r < 4; ++r) aacc[r] = __shfl(alpha, Lq * 4 + r);
#pragma unroll
        for (int dt = 0; dt < 8; ++dt)
#pragma unroll
          for (int r = 0; r < 4; ++r) acc[dt][r] *= aacc[r];
      }
      // ---- P = exp2(S - m), row sum ----
      float lsum = 0.f;
#pragma unroll
      for (int nt = 0; nt < 4; ++nt)
#pragma unroll
        for (int r = 0; r < 4; ++r) {
          sc[nt][r] = ex2(sc[nt][r] - m_i);
          lsum += sc[nt][r];
        }
      lsum += __shfl_xor(lsum, 16);
      lsum += __shfl_xor(lsum, 32);
      l_i += lsum;
      // ---- pack P pairs: w[nt][j] = k = nt*16 + Lq*4 + 2j + {0,1} ----
      u32 wA[2], wB[2], wC[2], wD[2];
      wA[0] = pkbf(sc[0][0], sc[0][1]); wA[1] = pkbf(sc[0][2], sc[0][3]);
      wB[0] = pkbf(sc[1][0], sc[1][1]); wB[1] = pkbf(sc[1][2], sc[1][3]);
      wC[0] = pkbf(sc[2][0], sc[2][1]); wC[1] = pkbf(sc[2][2], sc[2][3]);
      wD[0] = pkbf(sc[3][0], sc[3][1]); wD[1] = pkbf(sc[3][2], sc[3][3]);
      // ---- cross-lane repack -> pa[kc] = P[q=L15][k=kc*32+Lq*8+e] ----
      bf16x8 pa[2];
      {
        union { u32 u[4]; bf16x8 v; } t0, t1;
        u32 x0, x1;
        x0 = shf(wA[0], ls0); x1 = shf(wB[0], ls0); t0.u[0] = hi ? x1 : x0;
        x0 = shf(wA[1], ls0); x1 = shf(wB[1], ls0); t0.u[1] = hi ? x1 : x0;
        x0 = shf(wA[0], ls1); x1 = shf(wB[0], ls1); t0.u[2] = hi ? x1 : x0;
        x0 = shf(wA[1], ls1); x1 = shf(wB[1], ls1); t0.u[3] = hi ? x1 : x0;
        x0 = shf(wC[0], ls0); x1 = shf(wD[0], ls0); t1.u[0] = hi ? x1 : x0;
        x0 = shf(wC[1], ls0); x1 = shf(wD[1], ls0); t1.u[1] = hi ? x1 : x0;
        x0 = shf(wC[0], ls1); x1 = shf(wD[0], ls1); t1.u[2] = hi ? x1 : x0;
        x0 = shf(wC[1], ls1); x1 = shf(wD[1], ls1); t1.u[3] = hi ? x1 : x0;
        pa[0] = t0.v; pa[1] = t1.v;
      }
      // ---- M barrier: retire V(kt) only; K(kt+1) stays in flight ----
      if (kt + 1 < ktmax) asm volatile("s_waitcnt vmcnt(4)" ::: "memory");
      else                asm volatile("s_waitcnt vmcnt(0)" ::: "memory");
      __builtin_amdgcn_s_barrier();
      asm volatile("" ::: "memory");
      // ---- PV from Vs ----
#pragma unroll
      for (int dt = 0; dt < 8; ++dt)
#pragma unroll
        for (int kc = 0; kc < 2; ++kc) {
          const bf16x8 vf = *(const bf16x8*)&Vs[(dt * 16 + L15) * 64 + voff[kc]];
          acc[dt] = __builtin_amdgcn_mfma_f32_16x16x32_bf16(pa[kc], vf, acc[dt], 0, 0, 0);
        }
      __syncthreads();  // E: V reads done + K(kt+1) drained before next iter
    }
    // ---- epilogue ----
    {
      float inv[4];
#pragma unroll
      for (int r = 0; r < 4; ++r) inv[r] = 1.f / __shfl(l_i, Lq * 4 + r);
      u16* cp = ctx + ((size_t)b * S_ + base) * (NH * HD) + h * HD;
#pragma unroll
      for (int dt = 0; dt < 8; ++dt)
#pragma unroll
        for (int rp = 0; rp < 2; ++rp) {
          const u32 pk = pkbf(acc[dt][rp * 2] * inv[rp * 2],
                              acc[dt][rp * 2 + 1] * inv[rp * 2 + 1]);
          cp[(size_t)(Lq * 4 + rp * 2) * (NH * HD) + dt * 16 + L15] = (u16)pk;
          cp[(size_t)(Lq * 4 + rp * 2 + 1) * (NH * HD) + dt * 16 + L15] = (u16)(pk >> 16);
        }
    }
  }
}

extern "C" void kernel_launch(void* const* d_in, const int* in_sizes, int n_in,
                              void* d_out, int out_size, void* d_ws, size_t ws_size,
                              hipStream_t stream) {
  const float* x     = (const float*)d_in[0];
  const float* W_in  = (const float*)d_in[1];
  const float* b_in  = (const float*)d_in[2];
  const float* cw    = (const float*)d_in[3];
  const float* cb    = (const float*)d_in[4];
  const float* W_out = (const float*)d_in[5];
  const float* b_out = (const float*)d_in[6];

  char* ws = (char*)d_ws;
  u16* xb   = (u16*)(ws);                    // 16777216 B (dead after gemm1)
  u16* wib  = (u16*)(ws + 16777216);         // 12582912 B (dead after gemm1)
  u16* wob  = (u16*)(ws + 29360128);         //  8388608 B
  u16* qkv  = (u16*)(ws + 37748736);         // 25165824 B
  u16* q_ws = (u16*)(ws + 62914560);         // 16777216 B
  u16* k_ws = (u16*)(ws + 79691776);         //  4194304 B
  u16* vt_ws= (u16*)(ws + 83886080);         //  4194304 B
  u16* vtmp = wib;                           // v row-major, in dead wib region
  u16* ctx  = xb;                            // alias: xb dead after gemm1

  // 6 launches (was 9): f2b x3 fused, rope_tab folded into conv_rope.
  f2b3<<<dim3(18432), 256, 0, stream>>>(x, W_in, W_out, xb, wib, wob);
  gemm256<1><<<dim3(QKV_ / 256, (B_ * S_) / 256), 512, 0, stream>>>(
      xb, wib, b_in, (void*)qkv, B_ * S_, QKV_, E_);
  conv_rope<<<dim3(B_ * (S_ / SL)), 256, 0, stream>>>(qkv, cw, cb, q_ws, k_ws, vtmp);
  vtrans<<<dim3(S_ / 64, HD / 64, B_ * NKV), 256, 0, stream>>>(vtmp, vt_ws);
  attn<<<dim3(16, B_ * NH), 256, 0, stream>>>(q_ws, k_ws, vt_ws, ctx);
  gemm_n128<<<dim3(E_ / 128, (B_ * S_) / 256), 512, 0, stream>>>(
      ctx, wob, b_out, (float*)d_out, B_ * S_, E_, NH * HD);
}

// Round 11
// 320.663 us; speedup vs baseline: 1.1629x; 1.0102x over previous
//
#include <hip/hip_runtime.h>
#include <hip/hip_bf16.h>

#define B_   2
#define S_   2048
#define E_   2048
#define QKV_ 3072
#define NH   16
#define NKV  4
#define HD   128
#define SL   16   // conv_rope strip length

typedef __attribute__((ext_vector_type(8))) short bf16x8;
typedef __attribute__((ext_vector_type(4))) float f32x4;
typedef unsigned short u16;
typedef unsigned int   u32;

__device__ __forceinline__ float bf2f(u16 u) {
  union { u32 i; float f; } v; v.i = ((u32)u) << 16; return v.f;
}
__device__ __forceinline__ u16 f2bf(float f) {
  union { float f; u32 u; } v; v.f = f;
  return (u16)((v.u + 0x7FFFu + ((v.u >> 16) & 1u)) >> 16);
}
__device__ __forceinline__ u32 pkbf(float a, float b) {
  __hip_bfloat162 h = __float22bfloat162_rn(float2{a, b});
  u32 r; __builtin_memcpy(&r, &h, 4); return r;
}
__device__ __forceinline__ float ex2(float x) { return __builtin_amdgcn_exp2f(x); }
__device__ __forceinline__ u32 shf(u32 v, int l) { return (u32)__shfl((int)v, l); }
__device__ __forceinline__ void load_lds16(const u16* g, u16* l) {
  __builtin_amdgcn_global_load_lds((const __attribute__((address_space(1))) void*)g,
                                   (__attribute__((address_space(3))) void*)l, 16, 0, 0);
}

// ------- fused fp32 -> bf16 bulk convert for x, W_in, W_out (one launch) -------
__global__ __launch_bounds__(256) void f2b3(const float* __restrict__ x,
                                            const float* __restrict__ wi,
                                            const float* __restrict__ wo,
                                            u16* __restrict__ xb,
                                            u16* __restrict__ wib,
                                            u16* __restrict__ wob) {
  const int i = blockIdx.x * 256 + threadIdx.x;
  const float* src; u16* dst; int j;
  if (i < 2097152)            { src = x;  dst = xb;  j = i; }
  else if (i < 2097152 + 1572864) { src = wi; dst = wib; j = i - 2097152; }
  else                        { src = wo; dst = wob; j = i - 3670016; }
  const float4 v = ((const float4*)src)[j];
  ushort4 o;
  o.x = f2bf(v.x); o.y = f2bf(v.y); o.z = f2bf(v.z); o.w = f2bf(v.w);
  ((ushort4*)dst)[j] = o;
}

// ------------- 256x256 8-phase GEMM: C[M,N] = A[M,K]*B[N,K]^T + bias[N] -------------
// Round-10 change: 2 K-tiles unrolled per loop iteration -> COMPILE-TIME LDS buffer
// parity (m201 template's missing element). Same stage/read schedule as round 3
// (proof in those comments); only sm[BUF] indices became literals so ds_read /
// global_load_lds bases fold to immediates instead of per-use VALU address math.
template <int OUT_BF16>
__global__ __launch_bounds__(512, 2) void gemm256(const u16* __restrict__ A,
                                                  const u16* __restrict__ Bm,
                                                  const float* __restrict__ bias,
                                                  void* __restrict__ C,
                                                  int M, int N, int K) {
  __shared__ u16 sm[2][2][256 * 64];   // [buf][0=A,1=B][row*64 + unit*8 + e]
  const int tid = threadIdx.x;
  const int lane = tid & 63;
  const int wave = tid >> 6;
  const int wm = wave >> 2, wn = wave & 3;
  const int L15 = lane & 15, Lq = lane >> 4;
  const int m0 = blockIdx.y * 256, n0 = blockIdx.x * 256;
  const int NT = K >> 6;   // even (K multiple of 128)

  const int srow = tid >> 3;
  const int sdst = (tid & 7) * 8;
  const int ssrc = ((tid & 7) ^ (srow & 7)) * 8;

  f32x4 acc[8][4] = {};
  bf16x8 af[4][2], bf0[2][2], bf1[2][2];

#define STAGE_A(BUF, TC, H, J)                                                    \
  { const int row_ = (H) * 128 + (J) * 64 + srow;                                 \
    load_lds16(A + (size_t)(m0 + row_) * K + (TC) * 64 + ssrc,                    \
               &sm[BUF][0][row_ * 64 + sdst]); }
#define STAGE_B(BUF, TC, H, J)                                                    \
  { const int row_ = (H) * 128 + (J) * 64 + srow;                                 \
    load_lds16(Bm + (size_t)(n0 + row_) * K + (TC) * 64 + ssrc,                   \
               &sm[BUF][1][row_ * 64 + sdst]); }
#define RD_A(BUF, MS, MF, KK)                                                     \
  (*(const bf16x8*)&sm[BUF][0][(wm * 128 + (MS) * 64 + (MF) * 16 + L15) * 64 +    \
        ((((KK) * 4 + Lq) ^ ((wm * 128 + (MS) * 64 + (MF) * 16 + L15) & 7)) * 8)])
#define RD_B(BUF, NS, NF, KK)                                                     \
  (*(const bf16x8*)&sm[BUF][1][(wn * 64 + (NS) * 32 + (NF) * 16 + L15) * 64 +     \
        ((((KK) * 4 + Lq) ^ ((wn * 64 + (NS) * 32 + (NF) * 16 + L15) & 7)) * 8)])

#define MFMA_QUAD(MS, NS, BF)                                                     \
  __builtin_amdgcn_s_setprio(1);                                                  \
  _Pragma("unroll")                                                               \
  for (int kk = 0; kk < 2; ++kk)                                                  \
    _Pragma("unroll")                                                             \
    for (int mf = 0; mf < 4; ++mf)                                                \
      _Pragma("unroll")                                                           \
      for (int nf = 0; nf < 2; ++nf)                                              \
        acc[MS * 4 + mf][NS * 2 + nf] = __builtin_amdgcn_mfma_f32_16x16x32_bf16(  \
            af[mf][kk], BF[nf][kk], acc[MS * 4 + mf][NS * 2 + nf], 0, 0, 0);      \
  __builtin_amdgcn_s_setprio(0);

// One K-tile (4 phases). BUF literal; TT runtime tile index (global addr only).
// Schedule identical to round 3: p1 stages [TT+1:A1]->BUF^1, p2 [TT+1:B1]->BUF^1,
// p3 [TT+2:B0]->BUF (B reads retired at p2 end-bar), p4 [TT+2:A0]->BUF (A reads
// retired at p3 end-bar) + vmcnt(4) (leaves TT+2's 4 calls in flight).
#define TILE_BODY(BUF, TT)                                                        \
  {                                                                               \
    _Pragma("unroll")                                                             \
    for (int mf = 0; mf < 4; ++mf)                                                \
      _Pragma("unroll")                                                           \
      for (int kk = 0; kk < 2; ++kk) af[mf][kk] = RD_A(BUF, 0, mf, kk);           \
    _Pragma("unroll")                                                             \
    for (int nf = 0; nf < 2; ++nf)                                                \
      _Pragma("unroll")                                                           \
      for (int kk = 0; kk < 2; ++kk) bf0[nf][kk] = RD_B(BUF, 0, nf, kk);          \
    if ((TT) + 1 < NT) { STAGE_A(BUF ^ 1, (TT) + 1, 1, 0)                         \
                         STAGE_A(BUF ^ 1, (TT) + 1, 1, 1) }                       \
    __builtin_amdgcn_s_barrier();                                                 \
    MFMA_QUAD(0, 0, bf0)                                                          \
    __builtin_amdgcn_s_barrier();                                                 \
    _Pragma("unroll")                                                             \
    for (int nf = 0; nf < 2; ++nf)                                                \
      _Pragma("unroll")                                                           \
      for (int kk = 0; kk < 2; ++kk) bf1[nf][kk] = RD_B(BUF, 1, nf, kk);          \
    if ((TT) + 1 < NT) { STAGE_B(BUF ^ 1, (TT) + 1, 1, 0)                         \
                         STAGE_B(BUF ^ 1, (TT) + 1, 1, 1) }                       \
    __builtin_amdgcn_s_barrier();                                                 \
    MFMA_QUAD(0, 1, bf1)                                                          \
    __builtin_amdgcn_s_barrier();                                                 \
    _Pragma("unroll")                                                             \
    for (int mf = 0; mf < 4; ++mf)                                                \
      _Pragma("unroll")                                                           \
      for (int kk = 0; kk < 2; ++kk) af[mf][kk] = RD_A(BUF, 1, mf, kk);           \
    if ((TT) + 2 < NT) { STAGE_B(BUF, (TT) + 2, 0, 0)                             \
                         STAGE_B(BUF, (TT) + 2, 0, 1) }                           \
    __builtin_amdgcn_s_barrier();                                                 \
    MFMA_QUAD(1, 0, bf0)                                                          \
    __builtin_amdgcn_s_barrier();                                                 \
    if ((TT) + 2 < NT) {                                                          \
      STAGE_A(BUF, (TT) + 2, 0, 0)                                                \
      STAGE_A(BUF, (TT) + 2, 0, 1)                                                \
      asm volatile("s_waitcnt vmcnt(4)" ::: "memory");                            \
    } else {                                                                      \
      asm volatile("s_waitcnt vmcnt(0)" ::: "memory");                            \
    }                                                                             \
    __builtin_amdgcn_s_barrier();                                                 \
    MFMA_QUAD(1, 1, bf1)                                                          \
    __builtin_amdgcn_s_barrier();                                                 \
  }

  // prologue: tile0 {A0,B0,A1,B1}->buf0, tile1 {B0,A0}->buf1; vmcnt(4) allows
  // tile1's 4 calls in flight.
  STAGE_A(0, 0, 0, 0) STAGE_A(0, 0, 0, 1)
  STAGE_B(0, 0, 0, 0) STAGE_B(0, 0, 0, 1)
  STAGE_A(0, 0, 1, 0) STAGE_A(0, 0, 1, 1)
  STAGE_B(0, 0, 1, 0) STAGE_B(0, 0, 1, 1)
  STAGE_B(1, 1, 0, 0) STAGE_B(1, 1, 0, 1)
  STAGE_A(1, 1, 0, 0) STAGE_A(1, 1, 0, 1)
  asm volatile("s_waitcnt vmcnt(4)" ::: "memory");
  __builtin_amdgcn_s_barrier();

  for (int T = 0; T < NT; T += 2) {
    TILE_BODY(0, T)
    TILE_BODY(1, T + 1)
  }
#undef TILE_BODY
#undef MFMA_QUAD
#undef RD_B
#undef RD_A
#undef STAGE_B
#undef STAGE_A

  // ---- epilogue ----
#pragma unroll
  for (int ms = 0; ms < 2; ++ms)
#pragma unroll
    for (int mf = 0; mf < 4; ++mf) {
      const int grow0 = m0 + wm * 128 + ms * 64 + mf * 16 + Lq * 4;
#pragma unroll
      for (int ns = 0; ns < 2; ++ns)
#pragma unroll
        for (int nf = 0; nf < 2; ++nf) {
          const int gcol = n0 + wn * 64 + ns * 32 + nf * 16 + L15;
          const float bv = bias[gcol];
          const f32x4 v = acc[ms * 4 + mf][ns * 2 + nf];
#pragma unroll
          for (int r = 0; r < 4; ++r) {
            const float o = v[r] + bv;
            if (OUT_BF16) ((u16*)C)[(size_t)(grow0 + r) * N + gcol] = f2bf(o);
            else          ((float*)C)[(size_t)(grow0 + r) * N + gcol] = o;
          }
        }
    }
}

// ------------- 256x128 GEMM (grid-filling variant for N=2048): C = A*B^T + bias ----
// Round-10 change: 2 K-tiles unrolled -> compile-time buffer parity (same schedule).
__global__ __launch_bounds__(512, 2) void gemm_n128(const u16* __restrict__ A,
                                                    const u16* __restrict__ Bm,
                                                    const float* __restrict__ bias,
                                                    float* __restrict__ C,
                                                    int M, int N, int K) {
  __shared__ u16 sm[2][24576];  // [buf][ A 256*64 | B 128*64 ]
  const int tid = threadIdx.x, lane = tid & 63, wave = tid >> 6;
  const int wm = wave >> 1, wn = wave & 1;
  const int L15 = lane & 15, Lq = lane >> 4;
  const int m0 = blockIdx.y * 256, n0 = blockIdx.x * 128;
  const int NT = K >> 6;   // even

  const int srow = tid >> 3;
  const int sdst = (tid & 7) * 8;
  const int ssrc = ((tid & 7) ^ (srow & 7)) * 8;

  f32x4 acc[4][4] = {};

#define STAGE6(BUF, TC)                                                           \
  {                                                                               \
    _Pragma("unroll")                                                             \
    for (int c = 0; c < 4; ++c) {                                                 \
      const int row_ = c * 64 + srow;                                             \
      load_lds16(A + (size_t)(m0 + row_) * K + (TC) * 64 + ssrc,                  \
                 &sm[BUF][row_ * 64 + sdst]);                                     \
    }                                                                             \
    _Pragma("unroll")                                                             \
    for (int c = 0; c < 2; ++c) {                                                 \
      const int row_ = c * 64 + srow;                                             \
      load_lds16(Bm + (size_t)(n0 + row_) * K + (TC) * 64 + ssrc,                 \
                 &sm[BUF][16384 + row_ * 64 + sdst]);                             \
    }                                                                             \
  }

#define COMPUTE(BUF)                                                              \
  {                                                                               \
    bf16x8 af[4][2], bfr[4][2];                                                   \
    _Pragma("unroll")                                                             \
    for (int mf = 0; mf < 4; ++mf)                                                \
      _Pragma("unroll")                                                           \
      for (int kk = 0; kk < 2; ++kk) {                                            \
        const int row_ = wm * 64 + mf * 16 + L15;                                 \
        const int u_ = (kk * 4 + Lq) ^ (row_ & 7);                                \
        af[mf][kk] = *(const bf16x8*)&sm[BUF][row_ * 64 + u_ * 8];                \
      }                                                                           \
    _Pragma("unroll")                                                             \
    for (int nf = 0; nf < 4; ++nf)                                                \
      _Pragma("unroll")                                                           \
      for (int kk = 0; kk < 2; ++kk) {                                            \
        const int row_ = wn * 64 + nf * 16 + L15;                                 \
        const int u_ = (kk * 4 + Lq) ^ (row_ & 7);                                \
        bfr[nf][kk] = *(const bf16x8*)&sm[BUF][16384 + row_ * 64 + u_ * 8];       \
      }                                                                           \
    __builtin_amdgcn_s_setprio(1);                                                \
    _Pragma("unroll")                                                             \
    for (int kk = 0; kk < 2; ++kk)                                                \
      _Pragma("unroll")                                                           \
      for (int mf = 0; mf < 4; ++mf)                                              \
        _Pragma("unroll")                                                         \
        for (int nf = 0; nf < 4; ++nf)                                            \
          acc[mf][nf] = __builtin_amdgcn_mfma_f32_16x16x32_bf16(                  \
              af[mf][kk], bfr[nf][kk], acc[mf][nf], 0, 0, 0);                     \
    __builtin_amdgcn_s_setprio(0);                                                \
    __builtin_amdgcn_s_barrier();                                                 \
  }

  STAGE6(0, 0)
  for (int T = 0; T < NT; T += 2) {
    if (T + 1 < NT) {
      STAGE6(1, T + 1)
      asm volatile("s_waitcnt vmcnt(6)" ::: "memory");
    } else {
      asm volatile("s_waitcnt vmcnt(0)" ::: "memory");
    }
    __builtin_amdgcn_s_barrier();
    COMPUTE(0)
    if (T + 2 < NT) {
      STAGE6(0, T + 2)
      asm volatile("s_waitcnt vmcnt(6)" ::: "memory");
    } else {
      asm volatile("s_waitcnt vmcnt(0)" ::: "memory");
    }
    __builtin_amdgcn_s_barrier();
    COMPUTE(1)
  }
#undef COMPUTE
#undef STAGE6

  // ---- epilogue (fp32 + bias) ----
#pragma unroll
  for (int mf = 0; mf < 4; ++mf) {
    const int grow0 = m0 + wm * 64 + mf * 16 + Lq * 4;
#pragma unroll
    for (int nf = 0; nf < 4; ++nf) {
      const int gcol = n0 + wn * 64 + nf * 16 + L15;
      const float bv = bias[gcol];
#pragma unroll
      for (int r = 0; r < 4; ++r)
        C[(size_t)(grow0 + r) * N + gcol] = acc[mf][nf][r] + bv;
    }
  }
}

// ------------- depthwise causal conv(4) + bias + RoPE, streaming over s -------------
__global__ __launch_bounds__(256) void conv_rope(const u16* __restrict__ qkv,
                                                 const float* __restrict__ cw,
                                                 const float* __restrict__ cb,
                                                 u16* __restrict__ qo,
                                                 u16* __restrict__ ko,
                                                 u16* __restrict__ vtmp) {
  const int blk = blockIdx.x;                 // B * (S/SL)
  const int b = blk >> 7;                     // S/SL = 128
  const int s0 = (blk & 127) * SL;
  const u16* qb = qkv + (size_t)b * S_ * QKV_;

  for (int u = threadIdx.x; u < 896; u += 256) {
    if (u < 640) {
      // ---- rotary unit: features f1,f1+1 and f1+64,f1+65 ----
      const int hs = u >> 5, ip = u & 31, i = ip * 2;
      int f1; u16* outbase; float scale;
      if (hs < 16) {
        f1 = hs * HD + i;
        outbase = qo + (size_t)(b * NH + hs) * S_ * HD;
        scale = 0.08838834764831845f * 1.4426950408889634f;  // log2e/sqrt(128)
      } else {
        f1 = NH * HD + (hs - 16) * HD + i;
        outbase = ko + (size_t)(b * NKV + (hs - 16)) * S_ * HD;
        scale = 1.0f;
      }
      const float invf0 = powf(10000.0f, -(float)i * (1.0f / 64.0f));
      const float invf1 = powf(10000.0f, -(float)(i + 1) * (1.0f / 64.0f));
      const int f2 = f1 + 64;
      const float4 wA0 = *(const float4*)&cw[f1 * 4];
      const float4 wA1 = *(const float4*)&cw[(f1 + 1) * 4];
      const float4 wB0 = *(const float4*)&cw[f2 * 4];
      const float4 wB1 = *(const float4*)&cw[(f2 + 1) * 4];
      const float cA0 = cb[f1], cA1 = cb[f1 + 1], cB0 = cb[f2], cB1 = cb[f2 + 1];
      float A0[3], A1[3], B0[3], B1[3];
#pragma unroll
      for (int j = 0; j < 3; ++j) {
        const int t = s0 - 3 + j;
        if (t >= 0) {
          const u32 pa = *(const u32*)&qb[(size_t)t * QKV_ + f1];
          const u32 pb = *(const u32*)&qb[(size_t)t * QKV_ + f2];
          A0[j] = bf2f((u16)pa); A1[j] = bf2f((u16)(pa >> 16));
          B0[j] = bf2f((u16)pb); B1[j] = bf2f((u16)(pb >> 16));
        } else { A0[j] = A1[j] = B0[j] = B1[j] = 0.f; }
      }
      for (int s = s0; s < s0 + SL; ++s) {
        const u32 pa = *(const u32*)&qb[(size_t)s * QKV_ + f1];
        const u32 pb = *(const u32*)&qb[(size_t)s * QKV_ + f2];
        const float nA0 = bf2f((u16)pa), nA1 = bf2f((u16)(pa >> 16));
        const float nB0 = bf2f((u16)pb), nB1 = bf2f((u16)(pb >> 16));
        const float x1a = cA0 + wA0.x * A0[0] + wA0.y * A0[1] + wA0.z * A0[2] + wA0.w * nA0;
        const float x1b = cA1 + wA1.x * A1[0] + wA1.y * A1[1] + wA1.z * A1[2] + wA1.w * nA1;
        const float x2a = cB0 + wB0.x * B0[0] + wB0.y * B0[1] + wB0.z * B0[2] + wB0.w * nB0;
        const float x2b = cB1 + wB1.x * B1[0] + wB1.y * B1[1] + wB1.z * B1[2] + wB1.w * nB1;
        float sn0, cs0, sn1, cs1;
        sincosf((float)s * invf0, &sn0, &cs0);
        sincosf((float)s * invf1, &sn1, &cs1);
        u16* outp = outbase + (size_t)s * HD;
        *(u32*)&outp[i]      = pkbf((x1a * cs0 - x2a * sn0) * scale,
                                    (x1b * cs1 - x2b * sn1) * scale);
        *(u32*)&outp[i + 64] = pkbf((x2a * cs0 + x1a * sn0) * scale,
                                    (x2b * cs1 + x1b * sn1) * scale);
        A0[0] = A0[1]; A0[1] = A0[2]; A0[2] = nA0;
        A1[0] = A1[1]; A1[1] = A1[2]; A1[2] = nA1;
        B0[0] = B0[1]; B0[1] = B0[2]; B0[2] = nB0;
        B1[0] = B1[1]; B1[1] = B1[2]; B1[2] = nB1;
      }
    } else {
      // ---- v unit: features f, f+1 ----
      const int vu = u - 640, h = vu >> 6, d = (vu & 63) * 2;
      const int f = (NH + NKV) * HD + h * HD + d;
      const float4 w0 = *(const float4*)&cw[f * 4];
      const float4 w1 = *(const float4*)&cw[(f + 1) * 4];
      const float c0 = cb[f], c1 = cb[f + 1];
      float V0[3], V1[3];
#pragma unroll
      for (int j = 0; j < 3; ++j) {
        const int t = s0 - 3 + j;
        if (t >= 0) {
          const u32 p = *(const u32*)&qb[(size_t)t * QKV_ + f];
          V0[j] = bf2f((u16)p); V1[j] = bf2f((u16)(p >> 16));
        } else { V0[j] = V1[j] = 0.f; }
      }
      u16* vrow = vtmp + (size_t)(b * NKV + h) * S_ * HD + d;
      for (int s = s0; s < s0 + SL; ++s) {
        const u32 p = *(const u32*)&qb[(size_t)s * QKV_ + f];
        const float n0 = bf2f((u16)p), n1 = bf2f((u16)(p >> 16));
        const float v0 = c0 + w0.x * V0[0] + w0.y * V0[1] + w0.z * V0[2] + w0.w * n0;
        const float v1 = c1 + w1.x * V1[0] + w1.y * V1[1] + w1.z * V1[2] + w1.w * n1;
        *(u32*)&vrow[(size_t)s * HD] = pkbf(v0, v1);
        V0[0] = V0[1]; V0[1] = V0[2]; V0[2] = n0;
        V1[0] = V1[1]; V1[1] = V1[2]; V1[2] = n1;
      }
    }
  }
}

// ---------------- v (B,NKV,S,HD) -> v^T (B,NKV,HD,S), 64x64 LDS tiles ----------------
__global__ __launch_bounds__(256) void vtrans(const u16* __restrict__ vin,
                                              u16* __restrict__ vout) {
  __shared__ u16 t[64][72];
  const int bh = blockIdx.z;
  const int d0 = blockIdx.y * 64;
  const int s0 = blockIdx.x * 64;
  const u16* ip = vin + ((size_t)bh * S_ + s0) * HD + d0;
  const int r = threadIdx.x >> 4, c4 = (threadIdx.x & 15) * 4;
#pragma unroll
  for (int j = 0; j < 4; ++j) {
    const ushort4 v = *(const ushort4*)&ip[(size_t)(r + j * 16) * HD + c4];
    t[c4 + 0][r + j * 16] = v.x;
    t[c4 + 1][r + j * 16] = v.y;
    t[c4 + 2][r + j * 16] = v.z;
    t[c4 + 3][r + j * 16] = v.w;
  }
  __syncthreads();
  const int dl = threadIdx.x >> 2, sc = (threadIdx.x & 3) * 16;
  u16* op = vout + (size_t)bh * HD * S_ + (size_t)(d0 + dl) * S_ + s0 + sc;
  *(bf16x8*)op       = *(const bf16x8*)&t[dl][sc];
  *(bf16x8*)(op + 8) = *(const bf16x8*)&t[dl][sc + 8];
}

// ------------------------- flash attention (causal, GQA) -------------------------
// EXACT round-4 kernel (best measured: 78 µs; 87 on slower containers). Do not touch
// (r5/r6/r7 schedule experiments all regressed).
__global__ __launch_bounds__(256, 2) void attn(const u16* __restrict__ q,
                                               const u16* __restrict__ k,
                                               const u16* __restrict__ v,
                                               u16* __restrict__ ctx) {
  __shared__ u16 Ks[2][64 * 128];
  __shared__ u16 Vs[128 * 64];
  const int tid = threadIdx.x, wave = tid >> 6, lane = tid & 63;
  const int L15 = lane & 15, Lq = lane >> 4;
  const int bh = blockIdx.y;
  const int b = bh >> 4, h = bh & 15, hk = h >> 2;

  const u16* kb = k + (size_t)(b * NKV + hk) * S_ * HD;
  const u16* vb = v + (size_t)(b * NKV + hk) * HD * S_;

  const int rx = L15 & 7;
  int koff[4], voff[2];
#pragma unroll
  for (int c = 0; c < 4; ++c) koff[c] = ((c * 4 + Lq) ^ rx) * 8;
#pragma unroll
  for (int kc = 0; kc < 2; ++kc) voff[kc] = ((kc * 4 + Lq) ^ rx) * 8;

  const int ksl = tid >> 4, kcp = tid & 15;
  const int vsl = tid >> 3, vcp = tid & 7;

  const int ls0 = ((Lq & 1) << 5) + L15;
  const int ls1 = ls0 + 16;
  const bool hi = (Lq & 2) != 0;

  for (int pass = 0; pass < 2; ++pass) {
    const int qt = pass ? (31 - blockIdx.x) : blockIdx.x;
    const int q0 = qt * 64;
    const int base = q0 + wave * 16;

    bf16x8 qf[4];
    {
      const u16* qp = q + ((size_t)bh * S_ + base + L15) * HD + Lq * 8;
#pragma unroll
      for (int c = 0; c < 4; ++c) qf[c] = *(const bf16x8*)(qp + c * 32);
    }

    f32x4 acc[8] = {};
    float m_i = -1e30f, l_i = 0.f;   // per-lane scalars for q = base + L15

    const int ktmax = qt + 1;

    // preamble: stage K(0) and V(0)
#pragma unroll
    for (int j = 0; j < 4; ++j) {
      const int krow = j * 16 + ksl;
      load_lds16(kb + (size_t)krow * HD + (kcp ^ (krow & 7)) * 8,
                 &Ks[0][(krow * 16 + kcp) * 8]);
      const int vrow = j * 32 + vsl;
      load_lds16(vb + (size_t)vrow * S_ + (vcp ^ (vrow & 7)) * 8,
                 &Vs[(vrow * 8 + vcp) * 8]);
    }
    __syncthreads();

    for (int kt = 0; kt < ktmax; ++kt) {
      const int k0 = kt * 64;
      const int cur = kt & 1;
      if (kt > 0) {  // V(kt): buffer free since end-barrier of kt-1
#pragma unroll
        for (int j = 0; j < 4; ++j) {
          const int vrow = j * 32 + vsl;
          load_lds16(vb + (size_t)vrow * S_ + k0 + (vcp ^ (vrow & 7)) * 8,
                     &Vs[(vrow * 8 + vcp) * 8]);
        }
      }
      if (kt + 1 < ktmax) {  // K(kt+1) into other K buffer
        const int kn = k0 + 64;
#pragma unroll
        for (int j = 0; j < 4; ++j) {
          const int krow = j * 16 + ksl;
          load_lds16(kb + (size_t)(kn + krow) * HD + (kcp ^ (krow & 7)) * 8,
                     &Ks[cur ^ 1][(krow * 16 + kcp) * 8]);
        }
      }
      // ---- swapped QK^T: sc[nt][r] = S[q=base+L15][k=k0+nt*16+Lq*4+r] ----
      f32x4 sc[4];
#pragma unroll
      for (int nt = 0; nt < 4; ++nt) sc[nt] = f32x4{0.f, 0.f, 0.f, 0.f};
#pragma unroll
      for (int nt = 0; nt < 4; ++nt) {
#pragma unroll
        for (int c = 0; c < 4; ++c) {
          const bf16x8 kf = *(const bf16x8*)&Ks[cur][(nt * 16 + L15) * 128 + koff[c]];
          sc[nt] = __builtin_amdgcn_mfma_f32_16x16x32_bf16(kf, qf[c], sc[nt], 0, 0, 0);
        }
      }
      if (k0 + 63 > base) {  // diagonal tile: causal mask
#pragma unroll
        for (int nt = 0; nt < 4; ++nt)
#pragma unroll
          for (int r = 0; r < 4; ++r) {
            const int kidx = k0 + nt * 16 + Lq * 4 + r;
            if (kidx > base + L15) sc[nt][r] = -1e30f;
          }
      }
      // ---- row max (in-lane tree + 2 shfl) ----
      float mloc = fmaxf(fmaxf(fmaxf(sc[0][0], sc[0][1]), fmaxf(sc[0][2], sc[0][3])),
                         fmaxf(fmaxf(sc[1][0], sc[1][1]), fmaxf(sc[1][2], sc[1][3])));
      mloc = fmaxf(mloc,
                   fmaxf(fmaxf(fmaxf(sc[2][0], sc[2][1]), fmaxf(sc[2][2], sc[2][3])),
                         fmaxf(fmaxf(sc[3][0], sc[3][1]), fmaxf(sc[3][2], sc[3][3]))));
      mloc = fmaxf(mloc, __shfl_xor(mloc, 16));
      mloc = fmaxf(mloc, __shfl_xor(mloc, 32));
      // ---- defer-max online update ----
      const bool defer = __all(mloc - m_i <= 8.f);
      if (!defer) {
        const float mnew = fmaxf(m_i, mloc);
        const float alpha = ex2(m_i - mnew);
        m_i = mnew;
        l_i *= alpha;
        float aacc[4];
#pragma unroll
        for (int r = 0; r < 4; ++r) aacc[r] = __shfl(alpha, Lq * 4 + r);
#pragma unroll
        for (int dt = 0; dt < 8; ++dt)
#pragma unroll
          for (int r = 0; r < 4; ++r) acc[dt][r] *= aacc[r];
      }
      // ---- P = exp2(S - m), row sum ----
      float lsum = 0.f;
#pragma unroll
      for (int nt = 0; nt < 4; ++nt)
#pragma unroll
        for (int r = 0; r < 4; ++r) {
          sc[nt][r] = ex2(sc[nt][r] - m_i);
          lsum += sc[nt][r];
        }
      lsum += __shfl_xor(lsum, 16);
      lsum += __shfl_xor(lsum, 32);
      l_i += lsum;
      // ---- pack P pairs: w[nt][j] = k = nt*16 + Lq*4 + 2j + {0,1} ----
      u32 wA[2], wB[2], wC[2], wD[2];
      wA[0] = pkbf(sc[0][0], sc[0][1]); wA[1] = pkbf(sc[0][2], sc[0][3]);
      wB[0] = pkbf(sc[1][0], sc[1][1]); wB[1] = pkbf(sc[1][2], sc[1][3]);
      wC[0] = pkbf(sc[2][0], sc[2][1]); wC[1] = pkbf(sc[2][2], sc[2][3]);
      wD[0] = pkbf(sc[3][0], sc[3][1]); wD[1] = pkbf(sc[3][2], sc[3][3]);
      // ---- cross-lane repack -> pa[kc] = P[q=L15][k=kc*32+Lq*8+e] ----
      bf16x8 pa[2];
      {
        union { u32 u[4]; bf16x8 v; } t0, t1;
        u32 x0, x1;
        x0 = shf(wA[0], ls0); x1 = shf(wB[0], ls0); t0.u[0] = hi ? x1 : x0;
        x0 = shf(wA[1], ls0); x1 = shf(wB[1], ls0); t0.u[1] = hi ? x1 : x0;
        x0 = shf(wA[0], ls1); x1 = shf(wB[0], ls1); t0.u[2] = hi ? x1 : x0;
        x0 = shf(wA[1], ls1); x1 = shf(wB[1], ls1); t0.u[3] = hi ? x1 : x0;
        x0 = shf(wC[0], ls0); x1 = shf(wD[0], ls0); t1.u[0] = hi ? x1 : x0;
        x0 = shf(wC[1], ls0); x1 = shf(wD[1], ls0); t1.u[1] = hi ? x1 : x0;
        x0 = shf(wC[0], ls1); x1 = shf(wD[0], ls1); t1.u[2] = hi ? x1 : x0;
        x0 = shf(wC[1], ls1); x1 = shf(wD[1], ls1); t1.u[3] = hi ? x1 : x0;
        pa[0] = t0.v; pa[1] = t1.v;
      }
      // ---- M barrier: retire V(kt) only; K(kt+1) stays in flight ----
      if (kt + 1 < ktmax) asm volatile("s_waitcnt vmcnt(4)" ::: "memory");
      else                asm volatile("s_waitcnt vmcnt(0)" ::: "memory");
      __builtin_amdgcn_s_barrier();
      asm volatile("" ::: "memory");
      // ---- PV from Vs ----
#pragma unroll
      for (int dt = 0; dt < 8; ++dt)
#pragma unroll
        for (int kc = 0; kc < 2; ++kc) {
          const bf16x8 vf = *(const bf16x8*)&Vs[(dt * 16 + L15) * 64 + voff[kc]];
          acc[dt] = __builtin_amdgcn_mfma_f32_16x16x32_bf16(pa[kc], vf, acc[dt], 0, 0, 0);
        }
      __syncthreads();  // E: V reads done + K(kt+1) drained before next iter
    }
    // ---- epilogue ----
    {
      float inv[4];
#pragma unroll
      for (int r = 0; r < 4; ++r) inv[r] = 1.f / __shfl(l_i, Lq * 4 + r);
      u16* cp = ctx + ((size_t)b * S_ + base) * (NH * HD) + h * HD;
#pragma unroll
      for (int dt = 0; dt < 8; ++dt)
#pragma unroll
        for (int rp = 0; rp < 2; ++rp) {
          const u32 pk = pkbf(acc[dt][rp * 2] * inv[rp * 2],
                              acc[dt][rp * 2 + 1] * inv[rp * 2 + 1]);
          cp[(size_t)(Lq * 4 + rp * 2) * (NH * HD) + dt * 16 + L15] = (u16)pk;
          cp[(size_t)(Lq * 4 + rp * 2 + 1) * (NH * HD) + dt * 16 + L15] = (u16)(pk >> 16);
        }
    }
  }
}

extern "C" void kernel_launch(void* const* d_in, const int* in_sizes, int n_in,
                              void* d_out, int out_size, void* d_ws, size_t ws_size,
                              hipStream_t stream) {
  const float* x     = (const float*)d_in[0];
  const float* W_in  = (const float*)d_in[1];
  const float* b_in  = (const float*)d_in[2];
  const float* cw    = (const float*)d_in[3];
  const float* cb    = (const float*)d_in[4];
  const float* W_out = (const float*)d_in[5];
  const float* b_out = (const float*)d_in[6];

  char* ws = (char*)d_ws;
  u16* xb   = (u16*)(ws);                    // 16777216 B (dead after gemm1)
  u16* wib  = (u16*)(ws + 16777216);         // 12582912 B (dead after gemm1)
  u16* wob  = (u16*)(ws + 29360128);         //  8388608 B
  u16* qkv  = (u16*)(ws + 37748736);         // 25165824 B
  u16* q_ws = (u16*)(ws + 62914560);         // 16777216 B
  u16* k_ws = (u16*)(ws + 79691776);         //  4194304 B
  u16* vt_ws= (u16*)(ws + 83886080);         //  4194304 B
  u16* vtmp = wib;                           // v row-major, in dead wib region
  u16* ctx  = xb;                            // alias: xb dead after gemm1

  f2b3<<<dim3(18432), 256, 0, stream>>>(x, W_in, W_out, xb, wib, wob);
  gemm256<1><<<dim3(QKV_ / 256, (B_ * S_) / 256), 512, 0, stream>>>(
      xb, wib, b_in, (void*)qkv, B_ * S_, QKV_, E_);
  conv_rope<<<dim3(B_ * (S_ / SL)), 256, 0, stream>>>(qkv, cw, cb, q_ws, k_ws, vtmp);
  vtrans<<<dim3(S_ / 64, HD / 64, B_ * NKV), 256, 0, stream>>>(vtmp, vt_ws);
  attn<<<dim3(16, B_ * NH), 256, 0, stream>>>(q_ws, k_ws, vt_ws, ctx);
  gemm_n128<<<dim3(E_ / 128, (B_ * S_) / 256), 512, 0, stream>>>(
      ctx, wob, b_out, (float*)d_out, B_ * S_, E_, NH * HD);
}

// Round 12
// 297.085 us; speedup vs baseline: 1.2552x; 1.0794x over previous
//
#include <hip/hip_runtime.h>
#include <hip/hip_bf16.h>

#define B_   2
#define S_   2048
#define E_   2048
#define QKV_ 3072
#define NH   16
#define NKV  4
#define HD   128
#define SL   16   // conv_rope strip length

typedef __attribute__((ext_vector_type(8))) short bf16x8;
typedef __attribute__((ext_vector_type(4))) float f32x4;
typedef unsigned short u16;
typedef unsigned int   u32;

__device__ __forceinline__ float bf2f(u16 u) {
  union { u32 i; float f; } v; v.i = ((u32)u) << 16; return v.f;
}
__device__ __forceinline__ u16 f2bf(float f) {
  union { float f; u32 u; } v; v.f = f;
  return (u16)((v.u + 0x7FFFu + ((v.u >> 16) & 1u)) >> 16);
}
__device__ __forceinline__ u32 pkbf(float a, float b) {
  __hip_bfloat162 h = __float22bfloat162_rn(float2{a, b});
  u32 r; __builtin_memcpy(&r, &h, 4); return r;
}
__device__ __forceinline__ float ex2(float x) { return __builtin_amdgcn_exp2f(x); }
__device__ __forceinline__ u32 shf(u32 v, int l) { return (u32)__shfl((int)v, l); }
__device__ __forceinline__ void load_lds16(const u16* g, u16* l) {
  __builtin_amdgcn_global_load_lds((const __attribute__((address_space(1))) void*)g,
                                   (__attribute__((address_space(3))) void*)l, 16, 0, 0);
}

// ------- fused fp32 -> bf16 bulk convert for x, W_in, W_out (one launch) -------
__global__ __launch_bounds__(256) void f2b3(const float* __restrict__ x,
                                            const float* __restrict__ wi,
                                            const float* __restrict__ wo,
                                            u16* __restrict__ xb,
                                            u16* __restrict__ wib,
                                            u16* __restrict__ wob) {
  const int i = blockIdx.x * 256 + threadIdx.x;
  const float* src; u16* dst; int j;
  if (i < 2097152)            { src = x;  dst = xb;  j = i; }
  else if (i < 2097152 + 1572864) { src = wi; dst = wib; j = i - 2097152; }
  else                        { src = wo; dst = wob; j = i - 3670016; }
  const float4 v = ((const float4*)src)[j];
  ushort4 o;
  o.x = f2bf(v.x); o.y = f2bf(v.y); o.z = f2bf(v.z); o.w = f2bf(v.w);
  ((ushort4*)dst)[j] = o;
}

// ------------- 256x256 8-phase GEMM: C[M,N] = A[M,K]*B[N,K]^T + bias[N] -------------
// (unchanged from round 10/11 — 2 K-tiles unrolled, compile-time buffer parity)
template <int OUT_BF16>
__global__ __launch_bounds__(512, 2) void gemm256(const u16* __restrict__ A,
                                                  const u16* __restrict__ Bm,
                                                  const float* __restrict__ bias,
                                                  void* __restrict__ C,
                                                  int M, int N, int K) {
  __shared__ u16 sm[2][2][256 * 64];   // [buf][0=A,1=B][row*64 + unit*8 + e]
  const int tid = threadIdx.x;
  const int lane = tid & 63;
  const int wave = tid >> 6;
  const int wm = wave >> 2, wn = wave & 3;
  const int L15 = lane & 15, Lq = lane >> 4;
  const int m0 = blockIdx.y * 256, n0 = blockIdx.x * 256;
  const int NT = K >> 6;   // even (K multiple of 128)

  const int srow = tid >> 3;
  const int sdst = (tid & 7) * 8;
  const int ssrc = ((tid & 7) ^ (srow & 7)) * 8;

  f32x4 acc[8][4] = {};
  bf16x8 af[4][2], bf0[2][2], bf1[2][2];

#define STAGE_A(BUF, TC, H, J)                                                    \
  { const int row_ = (H) * 128 + (J) * 64 + srow;                                 \
    load_lds16(A + (size_t)(m0 + row_) * K + (TC) * 64 + ssrc,                    \
               &sm[BUF][0][row_ * 64 + sdst]); }
#define STAGE_B(BUF, TC, H, J)                                                    \
  { const int row_ = (H) * 128 + (J) * 64 + srow;                                 \
    load_lds16(Bm + (size_t)(n0 + row_) * K + (TC) * 64 + ssrc,                   \
               &sm[BUF][1][row_ * 64 + sdst]); }
#define RD_A(BUF, MS, MF, KK)                                                     \
  (*(const bf16x8*)&sm[BUF][0][(wm * 128 + (MS) * 64 + (MF) * 16 + L15) * 64 +    \
        ((((KK) * 4 + Lq) ^ ((wm * 128 + (MS) * 64 + (MF) * 16 + L15) & 7)) * 8)])
#define RD_B(BUF, NS, NF, KK)                                                     \
  (*(const bf16x8*)&sm[BUF][1][(wn * 64 + (NS) * 32 + (NF) * 16 + L15) * 64 +     \
        ((((KK) * 4 + Lq) ^ ((wn * 64 + (NS) * 32 + (NF) * 16 + L15) & 7)) * 8)])

#define MFMA_QUAD(MS, NS, BF)                                                     \
  __builtin_amdgcn_s_setprio(1);                                                  \
  _Pragma("unroll")                                                               \
  for (int kk = 0; kk < 2; ++kk)                                                  \
    _Pragma("unroll")                                                             \
    for (int mf = 0; mf < 4; ++mf)                                                \
      _Pragma("unroll")                                                           \
      for (int nf = 0; nf < 2; ++nf)                                              \
        acc[MS * 4 + mf][NS * 2 + nf] = __builtin_amdgcn_mfma_f32_16x16x32_bf16(  \
            af[mf][kk], BF[nf][kk], acc[MS * 4 + mf][NS * 2 + nf], 0, 0, 0);      \
  __builtin_amdgcn_s_setprio(0);

#define TILE_BODY(BUF, TT)                                                        \
  {                                                                               \
    _Pragma("unroll")                                                             \
    for (int mf = 0; mf < 4; ++mf)                                                \
      _Pragma("unroll")                                                           \
      for (int kk = 0; kk < 2; ++kk) af[mf][kk] = RD_A(BUF, 0, mf, kk);           \
    _Pragma("unroll")                                                             \
    for (int nf = 0; nf < 2; ++nf)                                                \
      _Pragma("unroll")                                                           \
      for (int kk = 0; kk < 2; ++kk) bf0[nf][kk] = RD_B(BUF, 0, nf, kk);          \
    if ((TT) + 1 < NT) { STAGE_A(BUF ^ 1, (TT) + 1, 1, 0)                         \
                         STAGE_A(BUF ^ 1, (TT) + 1, 1, 1) }                       \
    __builtin_amdgcn_s_barrier();                                                 \
    MFMA_QUAD(0, 0, bf0)                                                          \
    __builtin_amdgcn_s_barrier();                                                 \
    _Pragma("unroll")                                                             \
    for (int nf = 0; nf < 2; ++nf)                                                \
      _Pragma("unroll")                                                           \
      for (int kk = 0; kk < 2; ++kk) bf1[nf][kk] = RD_B(BUF, 1, nf, kk);          \
    if ((TT) + 1 < NT) { STAGE_B(BUF ^ 1, (TT) + 1, 1, 0)                         \
                         STAGE_B(BUF ^ 1, (TT) + 1, 1, 1) }                       \
    __builtin_amdgcn_s_barrier();                                                 \
    MFMA_QUAD(0, 1, bf1)                                                          \
    __builtin_amdgcn_s_barrier();                                                 \
    _Pragma("unroll")                                                             \
    for (int mf = 0; mf < 4; ++mf)                                                \
      _Pragma("unroll")                                                           \
      for (int kk = 0; kk < 2; ++kk) af[mf][kk] = RD_A(BUF, 1, mf, kk);           \
    if ((TT) + 2 < NT) { STAGE_B(BUF, (TT) + 2, 0, 0)                             \
                         STAGE_B(BUF, (TT) + 2, 0, 1) }                           \
    __builtin_amdgcn_s_barrier();                                                 \
    MFMA_QUAD(1, 0, bf0)                                                          \
    __builtin_amdgcn_s_barrier();                                                 \
    if ((TT) + 2 < NT) {                                                          \
      STAGE_A(BUF, (TT) + 2, 0, 0)                                                \
      STAGE_A(BUF, (TT) + 2, 0, 1)                                                \
      asm volatile("s_waitcnt vmcnt(4)" ::: "memory");                            \
    } else {                                                                      \
      asm volatile("s_waitcnt vmcnt(0)" ::: "memory");                            \
    }                                                                             \
    __builtin_amdgcn_s_barrier();                                                 \
    MFMA_QUAD(1, 1, bf1)                                                          \
    __builtin_amdgcn_s_barrier();                                                 \
  }

  STAGE_A(0, 0, 0, 0) STAGE_A(0, 0, 0, 1)
  STAGE_B(0, 0, 0, 0) STAGE_B(0, 0, 0, 1)
  STAGE_A(0, 0, 1, 0) STAGE_A(0, 0, 1, 1)
  STAGE_B(0, 0, 1, 0) STAGE_B(0, 0, 1, 1)
  STAGE_B(1, 1, 0, 0) STAGE_B(1, 1, 0, 1)
  STAGE_A(1, 1, 0, 0) STAGE_A(1, 1, 0, 1)
  asm volatile("s_waitcnt vmcnt(4)" ::: "memory");
  __builtin_amdgcn_s_barrier();

  for (int T = 0; T < NT; T += 2) {
    TILE_BODY(0, T)
    TILE_BODY(1, T + 1)
  }
#undef TILE_BODY
#undef MFMA_QUAD
#undef RD_B
#undef RD_A
#undef STAGE_B
#undef STAGE_A

  // ---- epilogue ----
#pragma unroll
  for (int ms = 0; ms < 2; ++ms)
#pragma unroll
    for (int mf = 0; mf < 4; ++mf) {
      const int grow0 = m0 + wm * 128 + ms * 64 + mf * 16 + Lq * 4;
#pragma unroll
      for (int ns = 0; ns < 2; ++ns)
#pragma unroll
        for (int nf = 0; nf < 2; ++nf) {
          const int gcol = n0 + wn * 64 + ns * 32 + nf * 16 + L15;
          const float bv = bias[gcol];
          const f32x4 v = acc[ms * 4 + mf][ns * 2 + nf];
#pragma unroll
          for (int r = 0; r < 4; ++r) {
            const float o = v[r] + bv;
            if (OUT_BF16) ((u16*)C)[(size_t)(grow0 + r) * N + gcol] = f2bf(o);
            else          ((float*)C)[(size_t)(grow0 + r) * N + gcol] = o;
          }
        }
    }
}

// ------------- 256x128 GEMM (grid-filling variant for N=2048): C = A*B^T + bias ----
// (unchanged from round 10/11)
__global__ __launch_bounds__(512, 2) void gemm_n128(const u16* __restrict__ A,
                                                    const u16* __restrict__ Bm,
                                                    const float* __restrict__ bias,
                                                    float* __restrict__ C,
                                                    int M, int N, int K) {
  __shared__ u16 sm[2][24576];  // [buf][ A 256*64 | B 128*64 ]
  const int tid = threadIdx.x, lane = tid & 63, wave = tid >> 6;
  const int wm = wave >> 1, wn = wave & 1;
  const int L15 = lane & 15, Lq = lane >> 4;
  const int m0 = blockIdx.y * 256, n0 = blockIdx.x * 128;
  const int NT = K >> 6;   // even

  const int srow = tid >> 3;
  const int sdst = (tid & 7) * 8;
  const int ssrc = ((tid & 7) ^ (srow & 7)) * 8;

  f32x4 acc[4][4] = {};

#define STAGE6(BUF, TC)                                                           \
  {                                                                               \
    _Pragma("unroll")                                                             \
    for (int c = 0; c < 4; ++c) {                                                 \
      const int row_ = c * 64 + srow;                                             \
      load_lds16(A + (size_t)(m0 + row_) * K + (TC) * 64 + ssrc,                  \
                 &sm[BUF][row_ * 64 + sdst]);                                     \
    }                                                                             \
    _Pragma("unroll")                                                             \
    for (int c = 0; c < 2; ++c) {                                                 \
      const int row_ = c * 64 + srow;                                             \
      load_lds16(Bm + (size_t)(n0 + row_) * K + (TC) * 64 + ssrc,                 \
                 &sm[BUF][16384 + row_ * 64 + sdst]);                             \
    }                                                                             \
  }

#define COMPUTE(BUF)                                                              \
  {                                                                               \
    bf16x8 af[4][2], bfr[4][2];                                                   \
    _Pragma("unroll")                                                             \
    for (int mf = 0; mf < 4; ++mf)                                                \
      _Pragma("unroll")                                                           \
      for (int kk = 0; kk < 2; ++kk) {                                            \
        const int row_ = wm * 64 + mf * 16 + L15;                                 \
        const int u_ = (kk * 4 + Lq) ^ (row_ & 7);                                \
        af[mf][kk] = *(const bf16x8*)&sm[BUF][row_ * 64 + u_ * 8];                \
      }                                                                           \
    _Pragma("unroll")                                                             \
    for (int nf = 0; nf < 4; ++nf)                                                \
      _Pragma("unroll")                                                           \
      for (int kk = 0; kk < 2; ++kk) {                                            \
        const int row_ = wn * 64 + nf * 16 + L15;                                 \
        const int u_ = (kk * 4 + Lq) ^ (row_ & 7);                                \
        bfr[nf][kk] = *(const bf16x8*)&sm[BUF][16384 + row_ * 64 + u_ * 8];       \
      }                                                                           \
    __builtin_amdgcn_s_setprio(1);                                                \
    _Pragma("unroll")                                                             \
    for (int kk = 0; kk < 2; ++kk)                                                \
      _Pragma("unroll")                                                           \
      for (int mf = 0; mf < 4; ++mf)                                              \
        _Pragma("unroll")                                                         \
        for (int nf = 0; nf < 4; ++nf)                                            \
          acc[mf][nf] = __builtin_amdgcn_mfma_f32_16x16x32_bf16(                  \
              af[mf][kk], bfr[nf][kk], acc[mf][nf], 0, 0, 0);                     \
    __builtin_amdgcn_s_setprio(0);                                                \
    __builtin_amdgcn_s_barrier();                                                 \
  }

  STAGE6(0, 0)
  for (int T = 0; T < NT; T += 2) {
    if (T + 1 < NT) {
      STAGE6(1, T + 1)
      asm volatile("s_waitcnt vmcnt(6)" ::: "memory");
    } else {
      asm volatile("s_waitcnt vmcnt(0)" ::: "memory");
    }
    __builtin_amdgcn_s_barrier();
    COMPUTE(0)
    if (T + 2 < NT) {
      STAGE6(0, T + 2)
      asm volatile("s_waitcnt vmcnt(6)" ::: "memory");
    } else {
      asm volatile("s_waitcnt vmcnt(0)" ::: "memory");
    }
    __builtin_amdgcn_s_barrier();
    COMPUTE(1)
  }
#undef COMPUTE
#undef STAGE6

  // ---- epilogue (fp32 + bias) ----
#pragma unroll
  for (int mf = 0; mf < 4; ++mf) {
    const int grow0 = m0 + wm * 64 + mf * 16 + Lq * 4;
#pragma unroll
    for (int nf = 0; nf < 4; ++nf) {
      const int gcol = n0 + wn * 64 + nf * 16 + L15;
      const float bv = bias[gcol];
#pragma unroll
      for (int r = 0; r < 4; ++r)
        C[(size_t)(grow0 + r) * N + gcol] = acc[mf][nf][r] + bv;
    }
  }
}

// ------------- depthwise causal conv(4) + bias + RoPE, streaming over s -------------
// Round-12: (1) per-block LDS rope table — the r7 inline fold recomputed each (s,i)
// sincos per rotary unit (20x redundancy, ~10M transcendentals); now computed once
// per block (4 sincosf/thread) into 8 KB LDS. (2) v units buffer 16 s-values in
// registers (static indices) and write v^T DIRECTLY -> vtrans kernel deleted.
__global__ __launch_bounds__(256) void conv_rope(const u16* __restrict__ qkv,
                                                 const float* __restrict__ cw,
                                                 const float* __restrict__ cb,
                                                 u16* __restrict__ qo,
                                                 u16* __restrict__ ko,
                                                 u16* __restrict__ vt) {
  __shared__ float ctab[SL][64], stab[SL][64];
  const int blk = blockIdx.x;                 // B * (S/SL)
  const int b = blk >> 7;                     // S/SL = 128
  const int s0 = (blk & 127) * SL;
  const u16* qb = qkv + (size_t)b * S_ * QKV_;

  // per-block rope table: 1024 (s,i) pairs, 4 per thread
  for (int idx = threadIdx.x; idx < SL * 64; idx += 256) {
    const int sl = idx >> 6, i = idx & 63;
    const float invf = powf(10000.0f, -(float)i * (1.0f / 64.0f));
    float sn, cs;
    sincosf((float)(s0 + sl) * invf, &sn, &cs);
    ctab[sl][i] = cs; stab[sl][i] = sn;
  }
  __syncthreads();

  for (int u = threadIdx.x; u < 896; u += 256) {
    if (u < 640) {
      // ---- rotary unit: features f1,f1+1 and f1+64,f1+65 ----
      const int hs = u >> 5, ip = u & 31, i = ip * 2;
      int f1; u16* outbase; float scale;
      if (hs < 16) {
        f1 = hs * HD + i;
        outbase = qo + (size_t)(b * NH + hs) * S_ * HD;
        scale = 0.08838834764831845f * 1.4426950408889634f;  // log2e/sqrt(128)
      } else {
        f1 = NH * HD + (hs - 16) * HD + i;
        outbase = ko + (size_t)(b * NKV + (hs - 16)) * S_ * HD;
        scale = 1.0f;
      }
      const int f2 = f1 + 64;
      const float4 wA0 = *(const float4*)&cw[f1 * 4];
      const float4 wA1 = *(const float4*)&cw[(f1 + 1) * 4];
      const float4 wB0 = *(const float4*)&cw[f2 * 4];
      const float4 wB1 = *(const float4*)&cw[(f2 + 1) * 4];
      const float cA0 = cb[f1], cA1 = cb[f1 + 1], cB0 = cb[f2], cB1 = cb[f2 + 1];
      float A0[3], A1[3], B0[3], B1[3];
#pragma unroll
      for (int j = 0; j < 3; ++j) {
        const int t = s0 - 3 + j;
        if (t >= 0) {
          const u32 pa = *(const u32*)&qb[(size_t)t * QKV_ + f1];
          const u32 pb = *(const u32*)&qb[(size_t)t * QKV_ + f2];
          A0[j] = bf2f((u16)pa); A1[j] = bf2f((u16)(pa >> 16));
          B0[j] = bf2f((u16)pb); B1[j] = bf2f((u16)(pb >> 16));
        } else { A0[j] = A1[j] = B0[j] = B1[j] = 0.f; }
      }
#pragma unroll
      for (int sl = 0; sl < SL; ++sl) {
        const int s = s0 + sl;
        const u32 pa = *(const u32*)&qb[(size_t)s * QKV_ + f1];
        const u32 pb = *(const u32*)&qb[(size_t)s * QKV_ + f2];
        const float nA0 = bf2f((u16)pa), nA1 = bf2f((u16)(pa >> 16));
        const float nB0 = bf2f((u16)pb), nB1 = bf2f((u16)(pb >> 16));
        const float x1a = cA0 + wA0.x * A0[0] + wA0.y * A0[1] + wA0.z * A0[2] + wA0.w * nA0;
        const float x1b = cA1 + wA1.x * A1[0] + wA1.y * A1[1] + wA1.z * A1[2] + wA1.w * nA1;
        const float x2a = cB0 + wB0.x * B0[0] + wB0.y * B0[1] + wB0.z * B0[2] + wB0.w * nB0;
        const float x2b = cB1 + wB1.x * B1[0] + wB1.y * B1[1] + wB1.z * B1[2] + wB1.w * nB1;
        const float2 cs = *(const float2*)&ctab[sl][i];
        const float2 sn = *(const float2*)&stab[sl][i];
        u16* outp = outbase + (size_t)s * HD;
        *(u32*)&outp[i]      = pkbf((x1a * cs.x - x2a * sn.x) * scale,
                                    (x1b * cs.y - x2b * sn.y) * scale);
        *(u32*)&outp[i + 64] = pkbf((x2a * cs.x + x1a * sn.x) * scale,
                                    (x2b * cs.y + x1b * sn.y) * scale);
        A0[0] = A0[1]; A0[1] = A0[2]; A0[2] = nA0;
        A1[0] = A1[1]; A1[1] = A1[2]; A1[2] = nA1;
        B0[0] = B0[1]; B0[1] = B0[2]; B0[2] = nB0;
        B1[0] = B1[1]; B1[1] = B1[2]; B1[2] = nB1;
      }
    } else {
      // ---- v unit: features f, f+1 -> buffered registers, direct v^T write ----
      const int vu = u - 640, h = vu >> 6, d = (vu & 63) * 2;
      const int f = (NH + NKV) * HD + h * HD + d;
      const float4 w0 = *(const float4*)&cw[f * 4];
      const float4 w1 = *(const float4*)&cw[(f + 1) * 4];
      const float c0 = cb[f], c1 = cb[f + 1];
      float V0[3], V1[3];
#pragma unroll
      for (int j = 0; j < 3; ++j) {
        const int t = s0 - 3 + j;
        if (t >= 0) {
          const u32 p = *(const u32*)&qb[(size_t)t * QKV_ + f];
          V0[j] = bf2f((u16)p); V1[j] = bf2f((u16)(p >> 16));
        } else { V0[j] = V1[j] = 0.f; }
      }
      union { u32 w[8]; bf16x8 v[2]; } R0, R1;
      float e0 = 0.f, e1 = 0.f;
#pragma unroll
      for (int sl = 0; sl < SL; ++sl) {
        const int s = s0 + sl;
        const u32 p = *(const u32*)&qb[(size_t)s * QKV_ + f];
        const float n0 = bf2f((u16)p), n1 = bf2f((u16)(p >> 16));
        const float v0 = c0 + w0.x * V0[0] + w0.y * V0[1] + w0.z * V0[2] + w0.w * n0;
        const float v1 = c1 + w1.x * V1[0] + w1.y * V1[1] + w1.z * V1[2] + w1.w * n1;
        if (sl & 1) { R0.w[sl >> 1] = pkbf(e0, v0); R1.w[sl >> 1] = pkbf(e1, v1); }
        else        { e0 = v0; e1 = v1; }
        V0[0] = V0[1]; V0[1] = V0[2]; V0[2] = n0;
        V1[0] = V1[1]; V1[1] = V1[2]; V1[2] = n1;
      }
      u16* vt0 = vt + ((size_t)(b * NKV + h) * HD + d) * S_ + s0;
      *(bf16x8*)vt0        = R0.v[0];
      *(bf16x8*)(vt0 + 8)  = R0.v[1];
      u16* vt1 = vt0 + S_;
      *(bf16x8*)vt1        = R1.v[0];
      *(bf16x8*)(vt1 + 8)  = R1.v[1];
    }
  }
}

// ------------------------- flash attention (causal, GQA) -------------------------
// EXACT round-4 kernel (best measured: 78 µs; 87 on slower containers). Do not touch
// (r5/r6/r7 schedule experiments all regressed).
__global__ __launch_bounds__(256, 2) void attn(const u16* __restrict__ q,
                                               const u16* __restrict__ k,
                                               const u16* __restrict__ v,
                                               u16* __restrict__ ctx) {
  __shared__ u16 Ks[2][64 * 128];
  __shared__ u16 Vs[128 * 64];
  const int tid = threadIdx.x, wave = tid >> 6, lane = tid & 63;
  const int L15 = lane & 15, Lq = lane >> 4;
  const int bh = blockIdx.y;
  const int b = bh >> 4, h = bh & 15, hk = h >> 2;

  const u16* kb = k + (size_t)(b * NKV + hk) * S_ * HD;
  const u16* vb = v + (size_t)(b * NKV + hk) * HD * S_;

  const int rx = L15 & 7;
  int koff[4], voff[2];
#pragma unroll
  for (int c = 0; c < 4; ++c) koff[c] = ((c * 4 + Lq) ^ rx) * 8;
#pragma unroll
  for (int kc = 0; kc < 2; ++kc) voff[kc] = ((kc * 4 + Lq) ^ rx) * 8;

  const int ksl = tid >> 4, kcp = tid & 15;
  const int vsl = tid >> 3, vcp = tid & 7;

  const int ls0 = ((Lq & 1) << 5) + L15;
  const int ls1 = ls0 + 16;
  const bool hi = (Lq & 2) != 0;

  for (int pass = 0; pass < 2; ++pass) {
    const int qt = pass ? (31 - blockIdx.x) : blockIdx.x;
    const int q0 = qt * 64;
    const int base = q0 + wave * 16;

    bf16x8 qf[4];
    {
      const u16* qp = q + ((size_t)bh * S_ + base + L15) * HD + Lq * 8;
#pragma unroll
      for (int c = 0; c < 4; ++c) qf[c] = *(const bf16x8*)(qp + c * 32);
    }

    f32x4 acc[8] = {};
    float m_i = -1e30f, l_i = 0.f;   // per-lane scalars for q = base + L15

    const int ktmax = qt + 1;

    // preamble: stage K(0) and V(0)
#pragma unroll
    for (int j = 0; j < 4; ++j) {
      const int krow = j * 16 + ksl;
      load_lds16(kb + (size_t)krow * HD + (kcp ^ (krow & 7)) * 8,
                 &Ks[0][(krow * 16 + kcp) * 8]);
      const int vrow = j * 32 + vsl;
      load_lds16(vb + (size_t)vrow * S_ + (vcp ^ (vrow & 7)) * 8,
                 &Vs[(vrow * 8 + vcp) * 8]);
    }
    __syncthreads();

    for (int kt = 0; kt < ktmax; ++kt) {
      const int k0 = kt * 64;
      const int cur = kt & 1;
      if (kt > 0) {  // V(kt): buffer free since end-barrier of kt-1
#pragma unroll
        for (int j = 0; j < 4; ++j) {
          const int vrow = j * 32 + vsl;
          load_lds16(vb + (size_t)vrow * S_ + k0 + (vcp ^ (vrow & 7)) * 8,
                     &Vs[(vrow * 8 + vcp) * 8]);
        }
      }
      if (kt + 1 < ktmax) {  // K(kt+1) into other K buffer
        const int kn = k0 + 64;
#pragma unroll
        for (int j = 0; j < 4; ++j) {
          const int krow = j * 16 + ksl;
          load_lds16(kb + (size_t)(kn + krow) * HD + (kcp ^ (krow & 7)) * 8,
                     &Ks[cur ^ 1][(krow * 16 + kcp) * 8]);
        }
      }
      // ---- swapped QK^T: sc[nt][r] = S[q=base+L15][k=k0+nt*16+Lq*4+r] ----
      f32x4 sc[4];
#pragma unroll
      for (int nt = 0; nt < 4; ++nt) sc[nt] = f32x4{0.f, 0.f, 0.f, 0.f};
#pragma unroll
      for (int nt = 0; nt < 4; ++nt) {
#pragma unroll
        for (int c = 0; c < 4; ++c) {
          const bf16x8 kf = *(const bf16x8*)&Ks[cur][(nt * 16 + L15) * 128 + koff[c]];
          sc[nt] = __builtin_amdgcn_mfma_f32_16x16x32_bf16(kf, qf[c], sc[nt], 0, 0, 0);
        }
      }
      if (k0 + 63 > base) {  // diagonal tile: causal mask
#pragma unroll
        for (int nt = 0; nt < 4; ++nt)
#pragma unroll
          for (int r = 0; r < 4; ++r) {
            const int kidx = k0 + nt * 16 + Lq * 4 + r;
            if (kidx > base + L15) sc[nt][r] = -1e30f;
          }
      }
      // ---- row max (in-lane tree + 2 shfl) ----
      float mloc = fmaxf(fmaxf(fmaxf(sc[0][0], sc[0][1]), fmaxf(sc[0][2], sc[0][3])),
                         fmaxf(fmaxf(sc[1][0], sc[1][1]), fmaxf(sc[1][2], sc[1][3])));
      mloc = fmaxf(mloc,
                   fmaxf(fmaxf(fmaxf(sc[2][0], sc[2][1]), fmaxf(sc[2][2], sc[2][3])),
                         fmaxf(fmaxf(sc[3][0], sc[3][1]), fmaxf(sc[3][2], sc[3][3]))));
      mloc = fmaxf(mloc, __shfl_xor(mloc, 16));
      mloc = fmaxf(mloc, __shfl_xor(mloc, 32));
      // ---- defer-max online update ----
      const bool defer = __all(mloc - m_i <= 8.f);
      if (!defer) {
        const float mnew = fmaxf(m_i, mloc);
        const float alpha = ex2(m_i - mnew);
        m_i = mnew;
        l_i *= alpha;
        float aacc[4];
#pragma unroll
        for (int r = 0; r < 4; ++r) aacc[r] = __shfl(alpha, Lq * 4 + r);
#pragma unroll
        for (int dt = 0; dt < 8; ++dt)
#pragma unroll
          for (int r = 0; r < 4; ++r) acc[dt][r] *= aacc[r];
      }
      // ---- P = exp2(S - m), row sum ----
      float lsum = 0.f;
#pragma unroll
      for (int nt = 0; nt < 4; ++nt)
#pragma unroll
        for (int r = 0; r < 4; ++r) {
          sc[nt][r] = ex2(sc[nt][r] - m_i);
          lsum += sc[nt][r];
        }
      lsum += __shfl_xor(lsum, 16);
      lsum += __shfl_xor(lsum, 32);
      l_i += lsum;
      // ---- pack P pairs: w[nt][j] = k = nt*16 + Lq*4 + 2j + {0,1} ----
      u32 wA[2], wB[2], wC[2], wD[2];
      wA[0] = pkbf(sc[0][0], sc[0][1]); wA[1] = pkbf(sc[0][2], sc[0][3]);
      wB[0] = pkbf(sc[1][0], sc[1][1]); wB[1] = pkbf(sc[1][2], sc[1][3]);
      wC[0] = pkbf(sc[2][0], sc[2][1]); wC[1] = pkbf(sc[2][2], sc[2][3]);
      wD[0] = pkbf(sc[3][0], sc[3][1]); wD[1] = pkbf(sc[3][2], sc[3][3]);
      // ---- cross-lane repack -> pa[kc] = P[q=L15][k=kc*32+Lq*8+e] ----
      bf16x8 pa[2];
      {
        union { u32 u[4]; bf16x8 v; } t0, t1;
        u32 x0, x1;
        x0 = shf(wA[0], ls0); x1 = shf(wB[0], ls0); t0.u[0] = hi ? x1 : x0;
        x0 = shf(wA[1], ls0); x1 = shf(wB[1], ls0); t0.u[1] = hi ? x1 : x0;
        x0 = shf(wA[0], ls1); x1 = shf(wB[0], ls1); t0.u[2] = hi ? x1 : x0;
        x0 = shf(wA[1], ls1); x1 = shf(wB[1], ls1); t0.u[3] = hi ? x1 : x0;
        x0 = shf(wC[0], ls0); x1 = shf(wD[0], ls0); t1.u[0] = hi ? x1 : x0;
        x0 = shf(wC[1], ls0); x1 = shf(wD[1], ls0); t1.u[1] = hi ? x1 : x0;
        x0 = shf(wC[0], ls1); x1 = shf(wD[0], ls1); t1.u[2] = hi ? x1 : x0;
        x0 = shf(wC[1], ls1); x1 = shf(wD[1], ls1); t1.u[3] = hi ? x1 : x0;
        pa[0] = t0.v; pa[1] = t1.v;
      }
      // ---- M barrier: retire V(kt) only; K(kt+1) stays in flight ----
      if (kt + 1 < ktmax) asm volatile("s_waitcnt vmcnt(4)" ::: "memory");
      else                asm volatile("s_waitcnt vmcnt(0)" ::: "memory");
      __builtin_amdgcn_s_barrier();
      asm volatile("" ::: "memory");
      // ---- PV from Vs ----
#pragma unroll
      for (int dt = 0; dt < 8; ++dt)
#pragma unroll
        for (int kc = 0; kc < 2; ++kc) {
          const bf16x8 vf = *(const bf16x8*)&Vs[(dt * 16 + L15) * 64 + voff[kc]];
          acc[dt] = __builtin_amdgcn_mfma_f32_16x16x32_bf16(pa[kc], vf, acc[dt], 0, 0, 0);
        }
      __syncthreads();  // E: V reads done + K(kt+1) drained before next iter
    }
    // ---- epilogue ----
    {
      float inv[4];
#pragma unroll
      for (int r = 0; r < 4; ++r) inv[r] = 1.f / __shfl(l_i, Lq * 4 + r);
      u16* cp = ctx + ((size_t)b * S_ + base) * (NH * HD) + h * HD;
#pragma unroll
      for (int dt = 0; dt < 8; ++dt)
#pragma unroll
        for (int rp = 0; rp < 2; ++rp) {
          const u32 pk = pkbf(acc[dt][rp * 2] * inv[rp * 2],
                              acc[dt][rp * 2 + 1] * inv[rp * 2 + 1]);
          cp[(size_t)(Lq * 4 + rp * 2) * (NH * HD) + dt * 16 + L15] = (u16)pk;
          cp[(size_t)(Lq * 4 + rp * 2 + 1) * (NH * HD) + dt * 16 + L15] = (u16)(pk >> 16);
        }
    }
  }
}

extern "C" void kernel_launch(void* const* d_in, const int* in_sizes, int n_in,
                              void* d_out, int out_size, void* d_ws, size_t ws_size,
                              hipStream_t stream) {
  const float* x     = (const float*)d_in[0];
  const float* W_in  = (const float*)d_in[1];
  const float* b_in  = (const float*)d_in[2];
  const float* cw    = (const float*)d_in[3];
  const float* cb    = (const float*)d_in[4];
  const float* W_out = (const float*)d_in[5];
  const float* b_out = (const float*)d_in[6];

  char* ws = (char*)d_ws;
  u16* xb   = (u16*)(ws);                    // 16777216 B (dead after gemm1)
  u16* wib  = (u16*)(ws + 16777216);         // 12582912 B (dead after gemm1)
  u16* wob  = (u16*)(ws + 29360128);         //  8388608 B
  u16* qkv  = (u16*)(ws + 37748736);         // 25165824 B
  u16* q_ws = (u16*)(ws + 62914560);         // 16777216 B
  u16* k_ws = (u16*)(ws + 79691776);         //  4194304 B
  u16* vt_ws= (u16*)(ws + 83886080);         //  4194304 B
  u16* ctx  = xb;                            // alias: xb dead after gemm1

  // 5 launches: f2b3, gemm1, conv_rope (writes v^T directly), attn, gemm2.
  f2b3<<<dim3(18432), 256, 0, stream>>>(x, W_in, W_out, xb, wib, wob);
  gemm256<1><<<dim3(QKV_ / 256, (B_ * S_) / 256), 512, 0, stream>>>(
      xb, wib, b_in, (void*)qkv, B_ * S_, QKV_, E_);
  conv_rope<<<dim3(B_ * (S_ / SL)), 256, 0, stream>>>(qkv, cw, cb, q_ws, k_ws, vt_ws);
  attn<<<dim3(16, B_ * NH), 256, 0, stream>>>(q_ws, k_ws, vt_ws, ctx);
  gemm_n128<<<dim3(E_ / 128, (B_ * S_) / 256), 512, 0, stream>>>(
      ctx, wob, b_out, (float*)d_out, B_ * S_, E_, NH * HD);
}